// Round 4
// baseline (710.807 us; speedup 1.0000x reference)
//
#include <hip/hip_runtime.h>
#include <hip/hip_bf16.h>

#define TB 256
#define BSH 7            // 128 nodes per bucket
#define BSZ 128
#define CHUNK 16384      // edges per block in bucket count/scatter

// Load element i of p as float, where p is either f32 (isf32=1) or bf16 bits (isf32=0).
__device__ __forceinline__ float ldany(const void* __restrict__ p, size_t i, int isf32) {
  if (isf32) return ((const float*)p)[i];
  unsigned int u = ((const unsigned short*)p)[i];
  return __uint_as_float(u << 16);
}

// Detect input float dtype: bf16 N(0,1) exponent field <= ~130; f32 misread as bf16
// gives uniform-random exponent fields, max >> 160 over 256 samples.
__global__ void detect_dtype(const unsigned short* __restrict__ xb, int* __restrict__ flag) {
  if (blockIdx.x == 0 && threadIdx.x == 0) {
    int mx = 0;
    for (int i = 0; i < 256; ++i) { int e = (xb[i] >> 7) & 0xFF; if (e > mx) mx = e; }
    *flag = (mx > 160) ? 1 : 0;   // 1 => inputs are float32
  }
}

// ---------------- bucket counting sort (by dst >> BSH) ----------------
__global__ void k_bcount(const int* __restrict__ ei, int E, int Et, int NB,
                         int* __restrict__ gcnt) {
  __shared__ int lcnt[1024];
  for (int i = threadIdx.x; i < NB; i += TB) lcnt[i] = 0;
  __syncthreads();
  long b0 = (long)blockIdx.x * CHUNK;
  int cnt = (int)(((long)Et - b0 < (long)CHUNK) ? ((long)Et - b0) : (long)CHUNK);
  for (int i = threadIdx.x; i < cnt; i += TB) {
    long e = b0 + i;
    int d = (e < E) ? ei[E + e] : (int)(e - E);
    atomicAdd(&lcnt[d >> BSH], 1);
  }
  __syncthreads();
  for (int i = threadIdx.x; i < NB; i += TB) {
    int c = lcnt[i];
    if (c) atomicAdd(&gcnt[i], c);
  }
}

// Exclusive scan over NB (<=1024) bucket counts; init cursor; set gbase[NB]=Et.
__global__ void k_bscan(const int* __restrict__ gcnt, int* __restrict__ gbase,
                        int* __restrict__ gcur, int NB, int Et) {
  __shared__ int sh[1024];
  int tid = threadIdx.x;
  int v = (tid < NB) ? gcnt[tid] : 0;
  sh[tid] = v;
  __syncthreads();
  for (int off = 1; off < 1024; off <<= 1) {
    int t = (tid >= off) ? sh[tid - off] : 0;
    __syncthreads();
    sh[tid] += t;
    __syncthreads();
  }
  if (tid < NB) { int b = sh[tid] - v; gbase[tid] = b; gcur[tid] = b; }
  if (tid == 0) gbase[NB] = Et;
}

// Scatter packed edges ((dst&127)<<17 | src) into bucket-ordered array.
// Per-block LDS histogram -> one global atomic per (block,bucket) -> grouped writes.
__global__ void k_bscatter(const int* __restrict__ ei, int E, int Et, int NB,
                           int* __restrict__ gcur, int* __restrict__ packed) {
  __shared__ int lcnt[1024];
  __shared__ int lbase[1024];
  for (int i = threadIdx.x; i < NB; i += TB) lcnt[i] = 0;
  __syncthreads();
  long b0 = (long)blockIdx.x * CHUNK;
  int cnt = (int)(((long)Et - b0 < (long)CHUNK) ? ((long)Et - b0) : (long)CHUNK);
  for (int i = threadIdx.x; i < cnt; i += TB) {
    long e = b0 + i;
    int d = (e < E) ? ei[E + e] : (int)(e - E);
    atomicAdd(&lcnt[d >> BSH], 1);
  }
  __syncthreads();
  for (int i = threadIdx.x; i < NB; i += TB) {
    int c = lcnt[i];
    lbase[i] = c ? atomicAdd(&gcur[i], c) : 0;
    lcnt[i] = 0;
  }
  __syncthreads();
  for (int i = threadIdx.x; i < cnt; i += TB) {
    long e = b0 + i;
    int s, d;
    if (e < E) { s = ei[e]; d = ei[E + e]; }
    else       { s = (int)(e - E); d = s; }
    int bk = d >> BSH;
    int pos = lbase[bk] + atomicAdd(&lcnt[bk], 1);
    packed[pos] = ((d & (BSZ - 1)) << 17) | s;
  }
}

// ---------------- Projection (layer 1 only): h = x@W1, row [h(C), als] per head ---
template<int FIN, int C, int RS, int HB>
__global__ void gat_proj(const void* __restrict__ xin,
                         const void* __restrict__ Wg,
                         const void* __restrict__ asg,
                         const void* __restrict__ adg,
                         float* __restrict__ hals,
                         float* __restrict__ ald,
                         int n, const int* __restrict__ flag) {
  const int isf = *flag;
  constexpr int FOUT = 2 * C;
  __shared__ float Ws[FIN * FOUT];
  __shared__ float as_s[FOUT], ad_s[FOUT];
  for (int i = threadIdx.x; i < FIN * FOUT; i += blockDim.x) Ws[i] = ldany(Wg, i, isf);
  if (threadIdx.x < FOUT) {
    as_s[threadIdx.x] = ldany(asg, threadIdx.x, isf);
    ad_s[threadIdx.x] = ldany(adg, threadIdx.x, isf);
  }
  __syncthreads();
  int nid = blockIdx.x * blockDim.x + threadIdx.x;
  if (nid >= n) return;

  float xr[FIN];
  #pragma unroll
  for (int i = 0; i < FIN; ++i) xr[i] = ldany(xin, (size_t)nid * FIN + i, isf);

  float hv[FOUT];
  #pragma unroll
  for (int j = 0; j < FOUT; ++j) hv[j] = 0.f;
  #pragma unroll
  for (int k = 0; k < FIN; ++k) {
    #pragma unroll
    for (int j = 0; j < FOUT; ++j) hv[j] += xr[k] * Ws[k * FOUT + j];
  }

  float* row = hals + (size_t)nid * RS;
  #pragma unroll
  for (int hh = 0; hh < 2; ++hh) {
    float s = 0.f, dd = 0.f;
    #pragma unroll
    for (int c = 0; c < C; ++c) {
      row[hh * HB + c] = hv[hh * C + c];
      s  += hv[hh * C + c] * as_s[hh * C + c];
      dd += hv[hh * C + c] * ad_s[hh * C + c];
    }
    row[hh * HB + C] = s;
    ald[(size_t)nid * 2 + hh] = dd;
  }
}

// ---------------- Bucketed edge reduce: LDS accumulators, fused finalize ---------
// Block = bucket of 128 dst nodes. Per edge: gather src row, w=exp(lrelu(.)),
// LDS ds_add_f32 into acc[dl][head][{h...,z}]. Finalize in-kernel.
// LAYER1: finalize applies bias+ELU then fuses proj2 (W2, att2) -> hals2/ald2.
// else:   finalize writes d_out (f32 or bf16 per flag).
template<int C, int RS, int HB, bool LAYER1>
__global__ void gat_edge(const int* __restrict__ gbase, const int* __restrict__ packed,
                         const float* __restrict__ hals, const float* __restrict__ ald,
                         const void* __restrict__ bias,
                         const void* __restrict__ W2g, const void* __restrict__ as2g,
                         const void* __restrict__ ad2g,
                         float* __restrict__ hals2, float* __restrict__ ald2,
                         void* __restrict__ outp,
                         int n, const int* __restrict__ flag) {
  constexpr int SLOT = 2 * (C + 1);
  __shared__ float acc[BSZ * SLOT];
  __shared__ float salD[BSZ * 2];
  __shared__ float sb[2 * C];
  __shared__ float W2s[LAYER1 ? 128 : 1];
  __shared__ float as2s[LAYER1 ? 8 : 1], ad2s[LAYER1 ? 8 : 1];
  const int isf = *flag;
  const int b = blockIdx.x;
  const int node0 = b << BSH;
  const int nn = min(BSZ, n - node0);

  for (int i = threadIdx.x; i < BSZ * SLOT; i += TB) acc[i] = 0.f;
  for (int i = threadIdx.x; i < nn * 2; i += TB) salD[i] = ald[(size_t)node0 * 2 + i];
  if (threadIdx.x < 2 * C) sb[threadIdx.x] = ldany(bias, threadIdx.x, isf);
  if constexpr (LAYER1) {
    for (int i = threadIdx.x; i < 128; i += TB) W2s[i] = ldany(W2g, i, isf);
    if (threadIdx.x < 8) {
      as2s[threadIdx.x] = ldany(as2g, threadIdx.x, isf);
      ad2s[threadIdx.x] = ldany(ad2g, threadIdx.x, isf);
    }
  }
  __syncthreads();

  const int beg = gbase[b], end = gbase[b + 1];
  for (int k = beg + threadIdx.x; k < end; k += TB) {
    int p = packed[k];
    int s = p & 0x1FFFF;
    int dl = p >> 17;
    const float* row = hals + (size_t)s * RS;
    #pragma unroll
    for (int hh = 0; hh < 2; ++hh) {
      const float4* r4 = (const float4*)(row + hh * HB);
      float hv[C];
      #pragma unroll
      for (int q = 0; q < C / 4; ++q) {
        float4 f = r4[q];
        hv[4 * q + 0] = f.x; hv[4 * q + 1] = f.y;
        hv[4 * q + 2] = f.z; hv[4 * q + 3] = f.w;
      }
      float lg = row[hh * HB + C] + salD[dl * 2 + hh];
      lg = lg > 0.f ? lg : 0.2f * lg;            // leaky_relu slope 0.2
      float w = __expf(lg);
      float* a = &acc[dl * SLOT + hh * (C + 1)];
      #pragma unroll
      for (int c = 0; c < C; ++c) unsafeAtomicAdd(&a[c], w * hv[c]);
      unsafeAtomicAdd(&a[C], w);
    }
  }
  __syncthreads();

  if (threadIdx.x < nn) {
    const int i = threadIdx.x;
    const int nid = node0 + i;
    float v[2 * C];
    #pragma unroll
    for (int hh = 0; hh < 2; ++hh) {
      float* a = &acc[i * SLOT + hh * (C + 1)];
      float inv = 1.f / (a[C] + 1e-16f);
      #pragma unroll
      for (int c = 0; c < C; ++c) {
        float t = a[c] * inv + sb[hh * C + c];
        if constexpr (LAYER1) t = t > 0.f ? t : expm1f(t);   // ELU
        v[hh * C + c] = t;
      }
    }
    if constexpr (LAYER1) {
      // fused proj2: h2 = v(16) @ W2(16x8); hals2 row stride 16, head hh at hh*8.
      float h2[8];
      #pragma unroll
      for (int j = 0; j < 8; ++j) h2[j] = 0.f;
      #pragma unroll
      for (int kk = 0; kk < 16; ++kk) {
        #pragma unroll
        for (int j = 0; j < 8; ++j) h2[j] += v[kk] * W2s[kk * 8 + j];
      }
      float* row2 = hals2 + (size_t)nid * 16;
      #pragma unroll
      for (int hh = 0; hh < 2; ++hh) {
        float s2 = 0.f, d2 = 0.f;
        #pragma unroll
        for (int c = 0; c < 4; ++c) {
          row2[hh * 8 + c] = h2[hh * 4 + c];
          s2 += h2[hh * 4 + c] * as2s[hh * 4 + c];
          d2 += h2[hh * 4 + c] * ad2s[hh * 4 + c];
        }
        row2[hh * 8 + 4] = s2;
        ald2[(size_t)nid * 2 + hh] = d2;
      }
    } else {
      #pragma unroll
      for (int j = 0; j < 2 * C; ++j) {
        size_t oi = (size_t)nid * (2 * C) + j;
        if (isf) ((float*)outp)[oi] = v[j];
        else     ((__hip_bfloat16*)outp)[oi] = __float2bfloat16(v[j]);
      }
    }
  }
}

extern "C" void kernel_launch(void* const* d_in, const int* in_sizes, int n_in,
                              void* d_out, int out_size, void* d_ws, size_t ws_size,
                              hipStream_t stream) {
  const void* x   = d_in[0];
  const int*  ei  = (const int*)d_in[1];
  const void* W1  = d_in[2];
  const void* as1 = d_in[3];
  const void* ad1 = d_in[4];
  const void* b1  = d_in[5];
  const void* W2  = d_in[6];
  const void* as2 = d_in[7];
  const void* ad2 = d_in[8];
  const void* b2  = d_in[9];

  const int n  = in_sizes[0] / 16;        // 100000
  const int E  = in_sizes[1] / 2;         // 3200000
  const int Et = E + n;                   // + self-loops
  const int NB = (n + BSZ - 1) >> BSH;    // 782 buckets

  // ---- workspace layout ----
  char* base = (char*)d_ws;
  int* flag   = (int*)base;               // 64 B
  int* gcnt   = (int*)(base + 64);        // NB+1
  int* gbase_ = gcnt + (NB + 1);          // NB+1
  int* gcur   = gbase_ + (NB + 1);        // NB
  int* packed = gcur + NB;                // Et
  size_t foff = 64 + sizeof(int) * ((size_t)(NB + 1) * 2 + NB + (size_t)Et);
  foff = (foff + 255) & ~(size_t)255;
  float* hals1 = (float*)(base + foff);            // 32n (stride 32: [h0(8),als0,pad, h1(8),als1,pad])
  float* ald1  = hals1 + (size_t)32 * n;           // 2n
  float* hals2 = ald1  + (size_t)2 * n;            // 16n (stride 16: [h0(4),als0,pad, h1(4),als1,pad])
  float* ald2  = hals2 + (size_t)16 * n;           // 2n

  const int nblk = (n + TB - 1) / TB;
  const int EB   = (Et + CHUNK - 1) / CHUNK;

  detect_dtype<<<1, 64, 0, stream>>>((const unsigned short*)x, flag);

  // ---- bucket counting sort (once; shared by both layers) ----
  hipMemsetAsync(gcnt, 0, (size_t)(NB + 1) * sizeof(int), stream);
  k_bcount<<<EB, TB, 0, stream>>>(ei, E, Et, NB, gcnt);
  k_bscan<<<1, 1024, 0, stream>>>(gcnt, gbase_, gcur, NB, Et);
  k_bscatter<<<EB, TB, 0, stream>>>(ei, E, Et, NB, gcur, packed);

  // ---- Layer 1 proj ----
  gat_proj<16, 8, 32, 16><<<nblk, TB, 0, stream>>>(x, W1, as1, ad1, hals1, ald1, n, flag);

  // ---- Layer 1 edge reduce + finalize + fused proj2 ----
  gat_edge<8, 32, 16, true><<<NB, TB, 0, stream>>>(gbase_, packed, hals1, ald1, b1,
                                                   W2, as2, ad2, hals2, ald2,
                                                   nullptr, n, flag);

  // ---- Layer 2 edge reduce + finalize -> d_out ----
  gat_edge<4, 16, 8, false><<<NB, TB, 0, stream>>>(gbase_, packed, hals2, ald2, b2,
                                                   nullptr, nullptr, nullptr,
                                                   nullptr, nullptr, d_out, n, flag);
}

// Round 5
// 253.079 us; speedup vs baseline: 2.8086x; 2.8086x over previous
//
#include <hip/hip_runtime.h>
#include <hip/hip_bf16.h>

#define TB 256
#define BSH 7            // 128 nodes per bucket
#define BSZ 128
#define CHUNK 16384      // edges per block in bucket count/scatter

// Load element i of p as float, where p is either f32 (isf32=1) or bf16 bits (isf32=0).
__device__ __forceinline__ float ldany(const void* __restrict__ p, size_t i, int isf32) {
  if (isf32) return ((const float*)p)[i];
  unsigned int u = ((const unsigned short*)p)[i];
  return __uint_as_float(u << 16);
}

// Detect input float dtype: bf16 N(0,1) exponent field <= ~130; f32 misread as bf16
// gives uniform-random exponent fields, max >> 160 over 256 samples.
__global__ void detect_dtype(const unsigned short* __restrict__ xb, int* __restrict__ flag) {
  int mx = 0;
  for (int i = threadIdx.x; i < 256; i += 64) { int e = (xb[i] >> 7) & 0xFF; mx = max(mx, e); }
  #pragma unroll
  for (int off = 32; off > 0; off >>= 1) mx = max(mx, __shfl_xor(mx, off));
  if (threadIdx.x == 0) *flag = (mx > 160) ? 1 : 0;   // 1 => inputs are float32
}

// ---------------- bucket counting sort (by dst >> BSH) ----------------
__global__ void k_bcount(const int* __restrict__ ei, int E, int Et, int NB,
                         int* __restrict__ gcnt) {
  __shared__ int lcnt[1024];
  for (int i = threadIdx.x; i < NB; i += TB) lcnt[i] = 0;
  __syncthreads();
  long b0 = (long)blockIdx.x * CHUNK;
  int cnt = (int)(((long)Et - b0 < (long)CHUNK) ? ((long)Et - b0) : (long)CHUNK);
  for (int i = threadIdx.x; i < cnt; i += TB) {
    long e = b0 + i;
    int d = (e < E) ? ei[E + e] : (int)(e - E);
    atomicAdd(&lcnt[d >> BSH], 1);
  }
  __syncthreads();
  for (int i = threadIdx.x; i < NB; i += TB) {
    int c = lcnt[i];
    if (c) atomicAdd(&gcnt[i], c);
  }
}

// Exclusive scan over NB (<=1024) bucket counts; init cursor; set gbase[NB]=Et.
__global__ void k_bscan(const int* __restrict__ gcnt, int* __restrict__ gbase,
                        int* __restrict__ gcur, int NB, int Et) {
  __shared__ int sh[1024];
  int tid = threadIdx.x;
  int v = (tid < NB) ? gcnt[tid] : 0;
  sh[tid] = v;
  __syncthreads();
  for (int off = 1; off < 1024; off <<= 1) {
    int t = (tid >= off) ? sh[tid - off] : 0;
    __syncthreads();
    sh[tid] += t;
    __syncthreads();
  }
  if (tid < NB) { int b = sh[tid] - v; gbase[tid] = b; gcur[tid] = b; }
  if (tid == 0) gbase[NB] = Et;
}

// Scatter packed edges ((dst&127)<<17 | src) into bucket-ordered array.
__global__ void k_bscatter(const int* __restrict__ ei, int E, int Et, int NB,
                           int* __restrict__ gcur, int* __restrict__ packed) {
  __shared__ int lcnt[1024];
  __shared__ int lbase[1024];
  for (int i = threadIdx.x; i < NB; i += TB) lcnt[i] = 0;
  __syncthreads();
  long b0 = (long)blockIdx.x * CHUNK;
  int cnt = (int)(((long)Et - b0 < (long)CHUNK) ? ((long)Et - b0) : (long)CHUNK);
  for (int i = threadIdx.x; i < cnt; i += TB) {
    long e = b0 + i;
    int d = (e < E) ? ei[E + e] : (int)(e - E);
    atomicAdd(&lcnt[d >> BSH], 1);
  }
  __syncthreads();
  for (int i = threadIdx.x; i < NB; i += TB) {
    int c = lcnt[i];
    lbase[i] = c ? atomicAdd(&gcur[i], c) : 0;
    lcnt[i] = 0;
  }
  __syncthreads();
  for (int i = threadIdx.x; i < cnt; i += TB) {
    long e = b0 + i;
    int s, d;
    if (e < E) { s = ei[e]; d = ei[E + e]; }
    else       { s = (int)(e - E); d = s; }
    int bk = d >> BSH;
    int pos = lbase[bk] + atomicAdd(&lcnt[bk], 1);
    packed[pos] = ((d & (BSZ - 1)) << 17) | s;
  }
}

// Local counting sort within each bucket -> full dst-sorted CSR + rowptr.
__global__ void k_localsort(const int* __restrict__ gbase, const int* __restrict__ packed,
                            int* __restrict__ rowptr, int* __restrict__ csr,
                            int n, int Et) {
  __shared__ int lcnt[BSZ], lbase[BSZ], lcur[BSZ], sh[BSZ];
  const int b = blockIdx.x;
  const int node0 = b << BSH;
  const int tid = threadIdx.x;
  for (int i = tid; i < BSZ; i += TB) lcnt[i] = 0;
  __syncthreads();
  const int beg = gbase[b], end = gbase[b + 1];
  for (int k = beg + tid; k < end; k += TB)
    atomicAdd(&lcnt[packed[k] >> 17], 1);
  __syncthreads();
  int v = (tid < BSZ) ? lcnt[tid] : 0;
  if (tid < BSZ) sh[tid] = v;
  __syncthreads();
  for (int off = 1; off < BSZ; off <<= 1) {
    int t = (tid < BSZ && tid >= off) ? sh[tid - off] : 0;
    __syncthreads();
    if (tid < BSZ) sh[tid] += t;
    __syncthreads();
  }
  if (tid < BSZ) { lbase[tid] = sh[tid] - v; lcur[tid] = 0; }
  __syncthreads();
  const int nn = min(BSZ, n - node0);
  if (tid < nn) rowptr[node0 + tid] = beg + lbase[tid];
  if (b == 0 && tid == 0) rowptr[n] = Et;
  for (int k = beg + tid; k < end; k += TB) {
    int p = packed[k];
    int dl = p >> 17;
    int pos = beg + lbase[dl] + atomicAdd(&lcur[dl], 1);
    csr[pos] = p & 0x1FFFF;
  }
}

// ---------------- Projection (layer 1): h = x@W1, row [h(C), als] per head ------
template<int FIN, int C, int RS, int HB>
__global__ void gat_proj(const void* __restrict__ xin,
                         const void* __restrict__ Wg,
                         const void* __restrict__ asg,
                         const void* __restrict__ adg,
                         float* __restrict__ hals,
                         float* __restrict__ ald,
                         int n, const int* __restrict__ flag) {
  const int isf = *flag;
  constexpr int FOUT = 2 * C;
  __shared__ float Ws[FIN * FOUT];
  __shared__ float as_s[FOUT], ad_s[FOUT];
  for (int i = threadIdx.x; i < FIN * FOUT; i += blockDim.x) Ws[i] = ldany(Wg, i, isf);
  if (threadIdx.x < FOUT) {
    as_s[threadIdx.x] = ldany(asg, threadIdx.x, isf);
    ad_s[threadIdx.x] = ldany(adg, threadIdx.x, isf);
  }
  __syncthreads();
  int nid = blockIdx.x * blockDim.x + threadIdx.x;
  if (nid >= n) return;

  float xr[FIN];
  #pragma unroll
  for (int i = 0; i < FIN; ++i) xr[i] = ldany(xin, (size_t)nid * FIN + i, isf);

  float hv[FOUT];
  #pragma unroll
  for (int j = 0; j < FOUT; ++j) hv[j] = 0.f;
  #pragma unroll
  for (int k = 0; k < FIN; ++k) {
    #pragma unroll
    for (int j = 0; j < FOUT; ++j) hv[j] += xr[k] * Ws[k * FOUT + j];
  }

  float* row = hals + (size_t)nid * RS;
  #pragma unroll
  for (int hh = 0; hh < 2; ++hh) {
    float s = 0.f, dd = 0.f;
    #pragma unroll
    for (int c = 0; c < C; ++c) {
      row[hh * HB + c] = hv[hh * C + c];
      s  += hv[hh * C + c] * as_s[hh * C + c];
      dd += hv[hh * C + c] * ad_s[hh * C + c];
    }
    row[hh * HB + C] = s;
    ald[(size_t)nid * 2 + hh] = dd;
  }
}

// ---------------- Gather: 4 threads per node = 2 heads x 2-way edge split -------
// Register accumulation + shfl combine. LAYER1: fused bias+ELU+proj2 -> hals2/ald2.
template<int C, int RS, int HB, bool LAYER1>
__global__ void gat_gather(const int* __restrict__ rowptr, const int* __restrict__ csr,
                           const float* __restrict__ hals, const float* __restrict__ ald,
                           const void* __restrict__ bias,
                           const void* __restrict__ W2g, const void* __restrict__ as2g,
                           const void* __restrict__ ad2g,
                           float* __restrict__ hals2, float* __restrict__ ald2,
                           void* __restrict__ outp, int n, const int* __restrict__ flag) {
  const int isf = *flag;
  __shared__ float sb[2 * C];
  __shared__ float sv[LAYER1 ? 64 * 16 : 1];
  __shared__ float W2s[LAYER1 ? 128 : 1];
  __shared__ float as2s[LAYER1 ? 8 : 1], ad2s[LAYER1 ? 8 : 1];
  if (threadIdx.x < 2 * C) sb[threadIdx.x] = ldany(bias, threadIdx.x, isf);
  if constexpr (LAYER1) {
    for (int i = threadIdx.x; i < 128; i += TB) W2s[i] = ldany(W2g, i, isf);
    if (threadIdx.x < 8) {
      as2s[threadIdx.x] = ldany(as2g, threadIdx.x, isf);
      ad2s[threadIdx.x] = ldany(ad2g, threadIdx.x, isf);
    }
  }
  __syncthreads();

  const int t = blockIdx.x * TB + threadIdx.x;
  const int half = t & 1, hh = (t >> 1) & 1, nid = t >> 2;
  const bool act = nid < n;
  int beg = 0, end = 0;
  float aldd = 0.f;
  if (act) {
    beg = rowptr[nid];
    end = rowptr[nid + 1];
    aldd = ald[(size_t)nid * 2 + hh];
  }

  float acc[C];
  #pragma unroll
  for (int c = 0; c < C; ++c) acc[c] = 0.f;
  float z = 0.f;

  for (int k = beg + half; k < end; k += 2) {
    int s = csr[k];
    const float* row = hals + (size_t)s * RS + hh * HB;
    float hv[C];
    #pragma unroll
    for (int q = 0; q < C / 4; ++q) {
      float4 f = ((const float4*)row)[q];
      hv[4 * q + 0] = f.x; hv[4 * q + 1] = f.y;
      hv[4 * q + 2] = f.z; hv[4 * q + 3] = f.w;
    }
    float lg = row[C] + aldd;
    lg = lg > 0.f ? lg : 0.2f * lg;            // leaky_relu slope 0.2
    float w = __expf(lg);
    z += w;
    #pragma unroll
    for (int c = 0; c < C; ++c) acc[c] += w * hv[c];
  }

  z += __shfl_xor(z, 1);
  #pragma unroll
  for (int c = 0; c < C; ++c) acc[c] += __shfl_xor(acc[c], 1);
  float inv = 1.f / (z + 1e-16f);

  if constexpr (LAYER1) {
    if (act && half == 0) {
      int ln = threadIdx.x >> 2;
      #pragma unroll
      for (int c = 0; c < C; ++c) {
        float v = acc[c] * inv + sb[hh * C + c];
        v = v > 0.f ? v : expm1f(v);            // ELU
        sv[ln * 16 + hh * C + c] = v;
      }
    }
    __syncthreads();
    int ln = threadIdx.x;
    if (ln < 64) {
      int nid2 = blockIdx.x * 64 + ln;
      if (nid2 < n) {
        float h2[8];
        #pragma unroll
        for (int j = 0; j < 8; ++j) h2[j] = 0.f;
        #pragma unroll
        for (int kk = 0; kk < 16; ++kk) {
          float v = sv[ln * 16 + kk];
          #pragma unroll
          for (int j = 0; j < 8; ++j) h2[j] += v * W2s[kk * 8 + j];
        }
        float* row2 = hals2 + (size_t)nid2 * 16;
        #pragma unroll
        for (int g = 0; g < 2; ++g) {
          float s2 = 0.f, d2 = 0.f;
          #pragma unroll
          for (int c = 0; c < 4; ++c) {
            row2[g * 8 + c] = h2[g * 4 + c];
            s2 += h2[g * 4 + c] * as2s[g * 4 + c];
            d2 += h2[g * 4 + c] * ad2s[g * 4 + c];
          }
          row2[g * 8 + 4] = s2;
          ald2[(size_t)nid2 * 2 + g] = d2;
        }
      }
    }
  } else {
    if (act && half == 0) {
      #pragma unroll
      for (int c = 0; c < C; ++c) {
        float v = acc[c] * inv + sb[hh * C + c];
        size_t oi = (size_t)nid * (2 * C) + hh * C + c;
        if (isf) ((float*)outp)[oi] = v;
        else     ((__hip_bfloat16*)outp)[oi] = __float2bfloat16(v);
      }
    }
  }
}

extern "C" void kernel_launch(void* const* d_in, const int* in_sizes, int n_in,
                              void* d_out, int out_size, void* d_ws, size_t ws_size,
                              hipStream_t stream) {
  const void* x   = d_in[0];
  const int*  ei  = (const int*)d_in[1];
  const void* W1  = d_in[2];
  const void* as1 = d_in[3];
  const void* ad1 = d_in[4];
  const void* b1  = d_in[5];
  const void* W2  = d_in[6];
  const void* as2 = d_in[7];
  const void* ad2 = d_in[8];
  const void* b2  = d_in[9];

  const int n  = in_sizes[0] / 16;        // 100000
  const int E  = in_sizes[1] / 2;         // 3200000
  const int Et = E + n;                   // + self-loops
  const int NB = (n + BSZ - 1) >> BSH;    // 782 buckets

  // ---- workspace layout ----
  char* base = (char*)d_ws;
  int* flag   = (int*)base;               // 64 B
  int* gcnt   = (int*)(base + 64);        // NB+1
  int* gbase_ = gcnt + (NB + 1);          // NB+1
  int* gcur   = gbase_ + (NB + 1);        // NB
  int* rowptr = gcur + NB;                // n+1
  int* csr    = rowptr + (n + 1);         // Et (persists through both gathers)
  size_t off1 = 64 + sizeof(int) * ((size_t)(NB + 1) * 2 + NB + (size_t)(n + 1) + (size_t)Et);
  off1 = (off1 + 255) & ~(size_t)255;
  // Union region: packed (Et ints, dead after localsort) / hals1+ald1 (34n floats,
  // written by gat_proj which runs after localsort).
  int*   packed = (int*)(base + off1);
  float* hals1  = (float*)(base + off1);          // stride 32: [h0(8),als0,pad(7), h1(8),als1,pad(7)]
  float* ald1   = hals1 + (size_t)32 * n;         // 2n
  size_t usz = sizeof(int) * (size_t)Et;
  size_t fsz = sizeof(float) * (size_t)34 * n;
  size_t off2 = off1 + (usz > fsz ? usz : fsz);
  off2 = (off2 + 255) & ~(size_t)255;
  float* hals2 = (float*)(base + off2);           // stride 16: [h0(4),als0,pad(3), h1(4),als1,pad(3)]
  float* ald2  = hals2 + (size_t)16 * n;          // 2n

  const int nblk = (n + TB - 1) / TB;
  const int EB   = (Et + CHUNK - 1) / CHUNK;
  const int gblk = (4 * n + TB - 1) / TB;         // 4 threads per node

  detect_dtype<<<1, 64, 0, stream>>>((const unsigned short*)x, flag);

  // ---- bucket counting sort -> dst-sorted CSR (once; shared by both layers) ----
  hipMemsetAsync(gcnt, 0, (size_t)(NB + 1) * sizeof(int), stream);
  k_bcount<<<EB, TB, 0, stream>>>(ei, E, Et, NB, gcnt);
  k_bscan<<<1, 1024, 0, stream>>>(gcnt, gbase_, gcur, NB, Et);
  k_bscatter<<<EB, TB, 0, stream>>>(ei, E, Et, NB, gcur, packed);
  k_localsort<<<NB, TB, 0, stream>>>(gbase_, packed, rowptr, csr, n, Et);

  // ---- Layer 1 proj (after localsort: hals1 overlaps packed) ----
  gat_proj<16, 8, 32, 16><<<nblk, TB, 0, stream>>>(x, W1, as1, ad1, hals1, ald1, n, flag);

  // ---- Layer 1 gather + finalize + fused proj2 ----
  gat_gather<8, 32, 16, true><<<gblk, TB, 0, stream>>>(rowptr, csr, hals1, ald1, b1,
                                                       W2, as2, ad2, hals2, ald2,
                                                       nullptr, n, flag);

  // ---- Layer 2 gather + finalize -> d_out ----
  gat_gather<4, 16, 8, false><<<gblk, TB, 0, stream>>>(rowptr, csr, hals2, ald2, b2,
                                                       nullptr, nullptr, nullptr,
                                                       nullptr, nullptr, d_out, n, flag);
}

// Round 6
// 224.159 us; speedup vs baseline: 3.1710x; 1.1290x over previous
//
#include <hip/hip_runtime.h>
#include <hip/hip_bf16.h>

#define TB 256
#define TBB 1024         // block size for edge count/scatter (occupancy!)
#define BSH 7            // 128 nodes per bucket
#define BSZ 128
#define CHUNK 16384      // edges per block in bucket count/scatter

// Load element i of p as float, where p is either f32 (isf32=1) or bf16 bits (isf32=0).
__device__ __forceinline__ float ldany(const void* __restrict__ p, size_t i, int isf32) {
  if (isf32) return ((const float*)p)[i];
  unsigned int u = ((const unsigned short*)p)[i];
  return __uint_as_float(u << 16);
}

// Detect input float dtype: bf16 N(0,1) exponent field <= ~130; f32 misread as bf16
// gives uniform-random exponent fields, max >> 160 over 256 samples.
__global__ void detect_dtype(const unsigned short* __restrict__ xb, int* __restrict__ flag) {
  int mx = 0;
  for (int i = threadIdx.x; i < 256; i += 64) { int e = (xb[i] >> 7) & 0xFF; mx = max(mx, e); }
  #pragma unroll
  for (int off = 32; off > 0; off >>= 1) mx = max(mx, __shfl_xor(mx, off));
  if (threadIdx.x == 0) *flag = (mx > 160) ? 1 : 0;   // 1 => inputs are float32
}

// ---------------- bucket counting sort (by dst >> BSH) ----------------
__global__ __launch_bounds__(TBB) void k_bcount(const int* __restrict__ ei, int E, int Et,
                                                int NB, int* __restrict__ gcnt) {
  __shared__ int lcnt[1024];
  for (int i = threadIdx.x; i < NB; i += TBB) lcnt[i] = 0;
  __syncthreads();
  long b0 = (long)blockIdx.x * CHUNK;
  int cnt = (int)(((long)Et - b0 < (long)CHUNK) ? ((long)Et - b0) : (long)CHUNK);
  for (int i = threadIdx.x * 4; i < cnt; i += TBB * 4) {
    long e = b0 + i;
    int rem = cnt - i;
    if (rem >= 4 && e + 3 < (long)E) {
      int4 d4 = *(const int4*)(ei + E + e);      // aligned: E%4==0, e%4==0
      atomicAdd(&lcnt[d4.x >> BSH], 1);
      atomicAdd(&lcnt[d4.y >> BSH], 1);
      atomicAdd(&lcnt[d4.z >> BSH], 1);
      atomicAdd(&lcnt[d4.w >> BSH], 1);
    } else {
      int m = rem < 4 ? rem : 4;
      for (int j = 0; j < m; ++j) {
        long ee = e + j;
        int d = (ee < E) ? ei[E + ee] : (int)(ee - E);
        atomicAdd(&lcnt[d >> BSH], 1);
      }
    }
  }
  __syncthreads();
  for (int i = threadIdx.x; i < NB; i += TBB) {
    int c = lcnt[i];
    if (c) atomicAdd(&gcnt[i], c);
  }
}

// Exclusive scan over NB (<=1024) bucket counts; init cursor; set gbase[NB]=Et.
__global__ void k_bscan(const int* __restrict__ gcnt, int* __restrict__ gbase,
                        int* __restrict__ gcur, int NB, int Et) {
  __shared__ int sh[1024];
  int tid = threadIdx.x;
  int v = (tid < NB) ? gcnt[tid] : 0;
  sh[tid] = v;
  __syncthreads();
  for (int off = 1; off < 1024; off <<= 1) {
    int t = (tid >= off) ? sh[tid - off] : 0;
    __syncthreads();
    sh[tid] += t;
    __syncthreads();
  }
  if (tid < NB) { int b = sh[tid] - v; gbase[tid] = b; gcur[tid] = b; }
  if (tid == 0) gbase[NB] = Et;
}

// Scatter packed edges ((dst&127)<<17 | src) into bucket-ordered array.
// Count chunk -> reserve per-bucket range (one global atomic) -> position via
// atomicAdd on the LDS cursor. Grouped ~64B+ writes per (block,bucket).
__global__ __launch_bounds__(TBB) void k_bscatter(const int* __restrict__ ei, int E, int Et,
                                                  int NB, int* __restrict__ gcur,
                                                  int* __restrict__ packed) {
  __shared__ int lcnt[1024];
  __shared__ int lbase[1024];
  for (int i = threadIdx.x; i < NB; i += TBB) lcnt[i] = 0;
  __syncthreads();
  long b0 = (long)blockIdx.x * CHUNK;
  int cnt = (int)(((long)Et - b0 < (long)CHUNK) ? ((long)Et - b0) : (long)CHUNK);
  for (int i = threadIdx.x * 4; i < cnt; i += TBB * 4) {
    long e = b0 + i;
    int rem = cnt - i;
    if (rem >= 4 && e + 3 < (long)E) {
      int4 d4 = *(const int4*)(ei + E + e);
      atomicAdd(&lcnt[d4.x >> BSH], 1);
      atomicAdd(&lcnt[d4.y >> BSH], 1);
      atomicAdd(&lcnt[d4.z >> BSH], 1);
      atomicAdd(&lcnt[d4.w >> BSH], 1);
    } else {
      int m = rem < 4 ? rem : 4;
      for (int j = 0; j < m; ++j) {
        long ee = e + j;
        int d = (ee < E) ? ei[E + ee] : (int)(ee - E);
        atomicAdd(&lcnt[d >> BSH], 1);
      }
    }
  }
  __syncthreads();
  for (int i = threadIdx.x; i < NB; i += TBB) {
    int c = lcnt[i];
    lbase[i] = c ? atomicAdd(&gcur[i], c) : 0;
  }
  __syncthreads();
  for (int i = threadIdx.x * 4; i < cnt; i += TBB * 4) {
    long e = b0 + i;
    int rem = cnt - i;
    if (rem >= 4 && e + 3 < (long)E) {
      int4 s4 = *(const int4*)(ei + e);
      int4 d4 = *(const int4*)(ei + E + e);
      int bk, pos;
      bk = d4.x >> BSH; pos = atomicAdd(&lbase[bk], 1); packed[pos] = ((d4.x & (BSZ-1)) << 17) | s4.x;
      bk = d4.y >> BSH; pos = atomicAdd(&lbase[bk], 1); packed[pos] = ((d4.y & (BSZ-1)) << 17) | s4.y;
      bk = d4.z >> BSH; pos = atomicAdd(&lbase[bk], 1); packed[pos] = ((d4.z & (BSZ-1)) << 17) | s4.z;
      bk = d4.w >> BSH; pos = atomicAdd(&lbase[bk], 1); packed[pos] = ((d4.w & (BSZ-1)) << 17) | s4.w;
    } else {
      int m = rem < 4 ? rem : 4;
      for (int j = 0; j < m; ++j) {
        long ee = e + j;
        int s, d;
        if (ee < E) { s = ei[ee]; d = ei[E + ee]; }
        else        { s = (int)(ee - E); d = s; }
        int bk = d >> BSH;
        int pos = atomicAdd(&lbase[bk], 1);
        packed[pos] = ((d & (BSZ - 1)) << 17) | s;
      }
    }
  }
}

// Local counting sort within each bucket -> full dst-sorted CSR + rowptr.
__global__ __launch_bounds__(512) void k_localsort(const int* __restrict__ gbase,
                                                   const int* __restrict__ packed,
                                                   int* __restrict__ rowptr,
                                                   int* __restrict__ csr,
                                                   int n, int Et) {
  __shared__ int lcnt[BSZ], lbase[BSZ], sh[BSZ];
  const int b = blockIdx.x;
  const int node0 = b << BSH;
  const int tid = threadIdx.x;
  if (tid < BSZ) lcnt[tid] = 0;
  __syncthreads();
  const int beg = gbase[b], end = gbase[b + 1];
  for (int k = beg + tid; k < end; k += 512)
    atomicAdd(&lcnt[packed[k] >> 17], 1);
  __syncthreads();
  int v = (tid < BSZ) ? lcnt[tid] : 0;
  if (tid < BSZ) sh[tid] = v;
  __syncthreads();
  for (int off = 1; off < BSZ; off <<= 1) {
    int t = (tid < BSZ && tid >= off) ? sh[tid - off] : 0;
    __syncthreads();
    if (tid < BSZ) sh[tid] += t;
    __syncthreads();
  }
  if (tid < BSZ) lbase[tid] = sh[tid] - v;
  __syncthreads();
  const int nn = min(BSZ, n - node0);
  if (tid < nn) rowptr[node0 + tid] = beg + lbase[tid];
  if (b == 0 && tid == 0) rowptr[n] = Et;
  for (int k = beg + tid; k < end; k += 512) {
    int p = packed[k];
    int dl = p >> 17;
    int pos = beg + atomicAdd(&lbase[dl], 1);
    csr[pos] = p & 0x1FFFF;
  }
}

// ---------------- Projection (layer 1): h = x@W1, row [h(C), als] per head ------
template<int FIN, int C, int RS, int HB>
__global__ void gat_proj(const void* __restrict__ xin,
                         const void* __restrict__ Wg,
                         const void* __restrict__ asg,
                         const void* __restrict__ adg,
                         float* __restrict__ hals,
                         float* __restrict__ ald,
                         int n, const int* __restrict__ flag) {
  const int isf = *flag;
  constexpr int FOUT = 2 * C;
  __shared__ float Ws[FIN * FOUT];
  __shared__ float as_s[FOUT], ad_s[FOUT];
  for (int i = threadIdx.x; i < FIN * FOUT; i += blockDim.x) Ws[i] = ldany(Wg, i, isf);
  if (threadIdx.x < FOUT) {
    as_s[threadIdx.x] = ldany(asg, threadIdx.x, isf);
    ad_s[threadIdx.x] = ldany(adg, threadIdx.x, isf);
  }
  __syncthreads();
  int nid = blockIdx.x * blockDim.x + threadIdx.x;
  if (nid >= n) return;

  float xr[FIN];
  #pragma unroll
  for (int i = 0; i < FIN; ++i) xr[i] = ldany(xin, (size_t)nid * FIN + i, isf);

  float hv[FOUT];
  #pragma unroll
  for (int j = 0; j < FOUT; ++j) hv[j] = 0.f;
  #pragma unroll
  for (int k = 0; k < FIN; ++k) {
    #pragma unroll
    for (int j = 0; j < FOUT; ++j) hv[j] += xr[k] * Ws[k * FOUT + j];
  }

  float* row = hals + (size_t)nid * RS;
  #pragma unroll
  for (int hh = 0; hh < 2; ++hh) {
    float s = 0.f, dd = 0.f;
    #pragma unroll
    for (int c = 0; c < C; ++c) {
      row[hh * HB + c] = hv[hh * C + c];
      s  += hv[hh * C + c] * as_s[hh * C + c];
      dd += hv[hh * C + c] * ad_s[hh * C + c];
    }
    row[hh * HB + C] = s;
    ald[(size_t)nid * 2 + hh] = dd;
  }
}

// ---------------- Gather: 4 threads per node = 2 heads x 2-way edge split -------
// Register accumulation + shfl combine. LAYER1: fused bias+ELU+proj2 -> hals2/ald2.
template<int C, int RS, int HB, bool LAYER1>
__global__ void gat_gather(const int* __restrict__ rowptr, const int* __restrict__ csr,
                           const float* __restrict__ hals, const float* __restrict__ ald,
                           const void* __restrict__ bias,
                           const void* __restrict__ W2g, const void* __restrict__ as2g,
                           const void* __restrict__ ad2g,
                           float* __restrict__ hals2, float* __restrict__ ald2,
                           void* __restrict__ outp, int n, const int* __restrict__ flag) {
  const int isf = *flag;
  __shared__ float sb[2 * C];
  __shared__ float sv[LAYER1 ? 64 * 16 : 1];
  __shared__ float W2s[LAYER1 ? 128 : 1];
  __shared__ float as2s[LAYER1 ? 8 : 1], ad2s[LAYER1 ? 8 : 1];
  if (threadIdx.x < 2 * C) sb[threadIdx.x] = ldany(bias, threadIdx.x, isf);
  if constexpr (LAYER1) {
    for (int i = threadIdx.x; i < 128; i += TB) W2s[i] = ldany(W2g, i, isf);
    if (threadIdx.x < 8) {
      as2s[threadIdx.x] = ldany(as2g, threadIdx.x, isf);
      ad2s[threadIdx.x] = ldany(ad2g, threadIdx.x, isf);
    }
  }
  __syncthreads();

  const int t = blockIdx.x * TB + threadIdx.x;
  const int half = t & 1, hh = (t >> 1) & 1, nid = t >> 2;
  const bool act = nid < n;
  int beg = 0, end = 0;
  float aldd = 0.f;
  if (act) {
    beg = rowptr[nid];
    end = rowptr[nid + 1];
    aldd = ald[(size_t)nid * 2 + hh];
  }

  float acc[C];
  #pragma unroll
  for (int c = 0; c < C; ++c) acc[c] = 0.f;
  float z = 0.f;

  for (int k = beg + half; k < end; k += 2) {
    int s = csr[k];
    const float* row = hals + (size_t)s * RS + hh * HB;
    float hv[C];
    #pragma unroll
    for (int q = 0; q < C / 4; ++q) {
      float4 f = ((const float4*)row)[q];
      hv[4 * q + 0] = f.x; hv[4 * q + 1] = f.y;
      hv[4 * q + 2] = f.z; hv[4 * q + 3] = f.w;
    }
    float lg = row[C] + aldd;
    lg = lg > 0.f ? lg : 0.2f * lg;            // leaky_relu slope 0.2
    float w = __expf(lg);
    z += w;
    #pragma unroll
    for (int c = 0; c < C; ++c) acc[c] += w * hv[c];
  }

  z += __shfl_xor(z, 1);
  #pragma unroll
  for (int c = 0; c < C; ++c) acc[c] += __shfl_xor(acc[c], 1);
  float inv = 1.f / (z + 1e-16f);

  if constexpr (LAYER1) {
    if (act && half == 0) {
      int ln = threadIdx.x >> 2;
      #pragma unroll
      for (int c = 0; c < C; ++c) {
        float v = acc[c] * inv + sb[hh * C + c];
        v = v > 0.f ? v : expm1f(v);            // ELU
        sv[ln * 16 + hh * C + c] = v;
      }
    }
    __syncthreads();
    int ln = threadIdx.x;
    if (ln < 64) {
      int nid2 = blockIdx.x * 64 + ln;
      if (nid2 < n) {
        float h2[8];
        #pragma unroll
        for (int j = 0; j < 8; ++j) h2[j] = 0.f;
        #pragma unroll
        for (int kk = 0; kk < 16; ++kk) {
          float v = sv[ln * 16 + kk];
          #pragma unroll
          for (int j = 0; j < 8; ++j) h2[j] += v * W2s[kk * 8 + j];
        }
        float* row2 = hals2 + (size_t)nid2 * 16;
        #pragma unroll
        for (int g = 0; g < 2; ++g) {
          float s2 = 0.f, d2 = 0.f;
          #pragma unroll
          for (int c = 0; c < 4; ++c) {
            row2[g * 8 + c] = h2[g * 4 + c];
            s2 += h2[g * 4 + c] * as2s[g * 4 + c];
            d2 += h2[g * 4 + c] * ad2s[g * 4 + c];
          }
          row2[g * 8 + 4] = s2;
          ald2[(size_t)nid2 * 2 + g] = d2;
        }
      }
    }
  } else {
    if (act && half == 0) {
      #pragma unroll
      for (int c = 0; c < C; ++c) {
        float v = acc[c] * inv + sb[hh * C + c];
        size_t oi = (size_t)nid * (2 * C) + hh * C + c;
        if (isf) ((float*)outp)[oi] = v;
        else     ((__hip_bfloat16*)outp)[oi] = __float2bfloat16(v);
      }
    }
  }
}

extern "C" void kernel_launch(void* const* d_in, const int* in_sizes, int n_in,
                              void* d_out, int out_size, void* d_ws, size_t ws_size,
                              hipStream_t stream) {
  const void* x   = d_in[0];
  const int*  ei  = (const int*)d_in[1];
  const void* W1  = d_in[2];
  const void* as1 = d_in[3];
  const void* ad1 = d_in[4];
  const void* b1  = d_in[5];
  const void* W2  = d_in[6];
  const void* as2 = d_in[7];
  const void* ad2 = d_in[8];
  const void* b2  = d_in[9];

  const int n  = in_sizes[0] / 16;        // 100000
  const int E  = in_sizes[1] / 2;         // 3200000
  const int Et = E + n;                   // + self-loops
  const int NB = (n + BSZ - 1) >> BSH;    // 782 buckets

  // ---- workspace layout ----
  char* base = (char*)d_ws;
  int* flag   = (int*)base;               // 64 B
  int* gcnt   = (int*)(base + 64);        // NB+1
  int* gbase_ = gcnt + (NB + 1);          // NB+1
  int* gcur   = gbase_ + (NB + 1);        // NB
  int* rowptr = gcur + NB;                // n+1
  int* csr    = rowptr + (n + 1);         // Et (persists through both gathers)
  size_t off1 = 64 + sizeof(int) * ((size_t)(NB + 1) * 2 + NB + (size_t)(n + 1) + (size_t)Et);
  off1 = (off1 + 255) & ~(size_t)255;
  // Union region: packed (Et ints, dead after localsort) / hals1+ald1 (34n floats,
  // written by gat_proj which runs after localsort).
  int*   packed = (int*)(base + off1);
  float* hals1  = (float*)(base + off1);          // stride 32: [h0(8),als0,pad(7), h1(8),als1,pad(7)]
  float* ald1   = hals1 + (size_t)32 * n;         // 2n
  size_t usz = sizeof(int) * (size_t)Et;
  size_t fsz = sizeof(float) * (size_t)34 * n;
  size_t off2 = off1 + (usz > fsz ? usz : fsz);
  off2 = (off2 + 255) & ~(size_t)255;
  float* hals2 = (float*)(base + off2);           // stride 16: [h0(4),als0,pad(3), h1(4),als1,pad(3)]
  float* ald2  = hals2 + (size_t)16 * n;          // 2n

  const int nblk = (n + TB - 1) / TB;
  const int EB   = (Et + CHUNK - 1) / CHUNK;
  const int gblk = (4 * n + TB - 1) / TB;         // 4 threads per node

  detect_dtype<<<1, 64, 0, stream>>>((const unsigned short*)x, flag);

  // ---- bucket counting sort -> dst-sorted CSR (once; shared by both layers) ----
  hipMemsetAsync(gcnt, 0, (size_t)(NB + 1) * sizeof(int), stream);
  k_bcount<<<EB, TBB, 0, stream>>>(ei, E, Et, NB, gcnt);
  k_bscan<<<1, 1024, 0, stream>>>(gcnt, gbase_, gcur, NB, Et);
  k_bscatter<<<EB, TBB, 0, stream>>>(ei, E, Et, NB, gcur, packed);
  k_localsort<<<NB, 512, 0, stream>>>(gbase_, packed, rowptr, csr, n, Et);

  // ---- Layer 1 proj (after localsort: hals1 overlaps packed) ----
  gat_proj<16, 8, 32, 16><<<nblk, TB, 0, stream>>>(x, W1, as1, ad1, hals1, ald1, n, flag);

  // ---- Layer 1 gather + finalize + fused proj2 ----
  gat_gather<8, 32, 16, true><<<gblk, TB, 0, stream>>>(rowptr, csr, hals1, ald1, b1,
                                                       W2, as2, ad2, hals2, ald2,
                                                       nullptr, n, flag);

  // ---- Layer 2 gather + finalize -> d_out ----
  gat_gather<4, 16, 8, false><<<gblk, TB, 0, stream>>>(rowptr, csr, hals2, ald2, b2,
                                                       nullptr, nullptr, nullptr,
                                                       nullptr, nullptr, d_out, n, flag);
}

// Round 7
// 204.040 us; speedup vs baseline: 3.4837x; 1.0986x over previous
//
#include <hip/hip_runtime.h>
#include <hip/hip_bf16.h>

#define TB 256
#define TBB 1024         // block size for edge count/scatter (occupancy!)
#define BSH 7            // 128 nodes per bucket
#define BSZ 128
#define CHUNK 16384      // edges per block in bucket count/scatter

// Load element i of p as float, where p is either f32 (isf32=1) or bf16 bits (isf32=0).
__device__ __forceinline__ float ldany(const void* __restrict__ p, size_t i, int isf32) {
  if (isf32) return ((const float*)p)[i];
  unsigned int u = ((const unsigned short*)p)[i];
  return __uint_as_float(u << 16);
}

// Detect input float dtype: bf16 N(0,1) exponent field <= ~130; f32 misread as bf16
// gives uniform-random exponent fields, max >> 160 over 256 samples.
__global__ void detect_dtype(const unsigned short* __restrict__ xb, int* __restrict__ flag) {
  int mx = 0;
  for (int i = threadIdx.x; i < 256; i += 64) { int e = (xb[i] >> 7) & 0xFF; mx = max(mx, e); }
  #pragma unroll
  for (int off = 32; off > 0; off >>= 1) mx = max(mx, __shfl_xor(mx, off));
  if (threadIdx.x == 0) *flag = (mx > 160) ? 1 : 0;   // 1 => inputs are float32
}

// ---------------- bucket counting sort (by dst >> BSH) ----------------
__global__ __launch_bounds__(TBB) void k_bcount(const int* __restrict__ ei, int E, int Et,
                                                int NB, int* __restrict__ gcnt) {
  __shared__ int lcnt[1024];
  for (int i = threadIdx.x; i < NB; i += TBB) lcnt[i] = 0;
  __syncthreads();
  long b0 = (long)blockIdx.x * CHUNK;
  int cnt = (int)(((long)Et - b0 < (long)CHUNK) ? ((long)Et - b0) : (long)CHUNK);
  for (int i = threadIdx.x * 4; i < cnt; i += TBB * 4) {
    long e = b0 + i;
    int rem = cnt - i;
    if (rem >= 4 && e + 3 < (long)E) {
      int4 d4 = *(const int4*)(ei + E + e);      // aligned: E%4==0, e%4==0
      atomicAdd(&lcnt[d4.x >> BSH], 1);
      atomicAdd(&lcnt[d4.y >> BSH], 1);
      atomicAdd(&lcnt[d4.z >> BSH], 1);
      atomicAdd(&lcnt[d4.w >> BSH], 1);
    } else {
      int m = rem < 4 ? rem : 4;
      for (int j = 0; j < m; ++j) {
        long ee = e + j;
        int d = (ee < E) ? ei[E + ee] : (int)(ee - E);
        atomicAdd(&lcnt[d >> BSH], 1);
      }
    }
  }
  __syncthreads();
  for (int i = threadIdx.x; i < NB; i += TBB) {
    int c = lcnt[i];
    if (c) atomicAdd(&gcnt[i], c);
  }
}

// Exclusive scan over NB (<=1024) bucket counts; init cursor; set gbase[NB]=Et.
__global__ void k_bscan(const int* __restrict__ gcnt, int* __restrict__ gbase,
                        int* __restrict__ gcur, int NB, int Et) {
  __shared__ int sh[1024];
  int tid = threadIdx.x;
  int v = (tid < NB) ? gcnt[tid] : 0;
  sh[tid] = v;
  __syncthreads();
  for (int off = 1; off < 1024; off <<= 1) {
    int t = (tid >= off) ? sh[tid - off] : 0;
    __syncthreads();
    sh[tid] += t;
    __syncthreads();
  }
  if (tid < NB) { int b = sh[tid] - v; gbase[tid] = b; gcur[tid] = b; }
  if (tid == 0) gbase[NB] = Et;
}

// Scatter packed edges ((dst&127)<<17 | src) into bucket-ordered array.
__global__ __launch_bounds__(TBB) void k_bscatter(const int* __restrict__ ei, int E, int Et,
                                                  int NB, int* __restrict__ gcur,
                                                  int* __restrict__ packed) {
  __shared__ int lcnt[1024];
  __shared__ int lbase[1024];
  for (int i = threadIdx.x; i < NB; i += TBB) lcnt[i] = 0;
  __syncthreads();
  long b0 = (long)blockIdx.x * CHUNK;
  int cnt = (int)(((long)Et - b0 < (long)CHUNK) ? ((long)Et - b0) : (long)CHUNK);
  for (int i = threadIdx.x * 4; i < cnt; i += TBB * 4) {
    long e = b0 + i;
    int rem = cnt - i;
    if (rem >= 4 && e + 3 < (long)E) {
      int4 d4 = *(const int4*)(ei + E + e);
      atomicAdd(&lcnt[d4.x >> BSH], 1);
      atomicAdd(&lcnt[d4.y >> BSH], 1);
      atomicAdd(&lcnt[d4.z >> BSH], 1);
      atomicAdd(&lcnt[d4.w >> BSH], 1);
    } else {
      int m = rem < 4 ? rem : 4;
      for (int j = 0; j < m; ++j) {
        long ee = e + j;
        int d = (ee < E) ? ei[E + ee] : (int)(ee - E);
        atomicAdd(&lcnt[d >> BSH], 1);
      }
    }
  }
  __syncthreads();
  for (int i = threadIdx.x; i < NB; i += TBB) {
    int c = lcnt[i];
    lbase[i] = c ? atomicAdd(&gcur[i], c) : 0;
  }
  __syncthreads();
  for (int i = threadIdx.x * 4; i < cnt; i += TBB * 4) {
    long e = b0 + i;
    int rem = cnt - i;
    if (rem >= 4 && e + 3 < (long)E) {
      int4 s4 = *(const int4*)(ei + e);
      int4 d4 = *(const int4*)(ei + E + e);
      int bk, pos;
      bk = d4.x >> BSH; pos = atomicAdd(&lbase[bk], 1); packed[pos] = ((d4.x & (BSZ-1)) << 17) | s4.x;
      bk = d4.y >> BSH; pos = atomicAdd(&lbase[bk], 1); packed[pos] = ((d4.y & (BSZ-1)) << 17) | s4.y;
      bk = d4.z >> BSH; pos = atomicAdd(&lbase[bk], 1); packed[pos] = ((d4.z & (BSZ-1)) << 17) | s4.z;
      bk = d4.w >> BSH; pos = atomicAdd(&lbase[bk], 1); packed[pos] = ((d4.w & (BSZ-1)) << 17) | s4.w;
    } else {
      int m = rem < 4 ? rem : 4;
      for (int j = 0; j < m; ++j) {
        long ee = e + j;
        int s, d;
        if (ee < E) { s = ei[ee]; d = ei[E + ee]; }
        else        { s = (int)(ee - E); d = s; }
        int bk = d >> BSH;
        int pos = atomicAdd(&lbase[bk], 1);
        packed[pos] = ((d & (BSZ - 1)) << 17) | s;
      }
    }
  }
}

// Local counting sort within each bucket -> full dst-sorted CSR + rowptr.
__global__ __launch_bounds__(512) void k_localsort(const int* __restrict__ gbase,
                                                   const int* __restrict__ packed,
                                                   int* __restrict__ rowptr,
                                                   int* __restrict__ csr,
                                                   int n, int Et) {
  __shared__ int lcnt[BSZ], lbase[BSZ], sh[BSZ];
  const int b = blockIdx.x;
  const int node0 = b << BSH;
  const int tid = threadIdx.x;
  if (tid < BSZ) lcnt[tid] = 0;
  __syncthreads();
  const int beg = gbase[b], end = gbase[b + 1];
  for (int k = beg + tid; k < end; k += 512)
    atomicAdd(&lcnt[packed[k] >> 17], 1);
  __syncthreads();
  int v = (tid < BSZ) ? lcnt[tid] : 0;
  if (tid < BSZ) sh[tid] = v;
  __syncthreads();
  for (int off = 1; off < BSZ; off <<= 1) {
    int t = (tid < BSZ && tid >= off) ? sh[tid - off] : 0;
    __syncthreads();
    if (tid < BSZ) sh[tid] += t;
    __syncthreads();
  }
  if (tid < BSZ) lbase[tid] = sh[tid] - v;
  __syncthreads();
  const int nn = min(BSZ, n - node0);
  if (tid < nn) rowptr[node0 + tid] = beg + lbase[tid];
  if (b == 0 && tid == 0) rowptr[n] = Et;
  for (int k = beg + tid; k < end; k += 512) {
    int p = packed[k];
    int dl = p >> 17;
    int pos = beg + atomicAdd(&lbase[dl], 1);
    csr[pos] = p & 0x1FFFF;
  }
}

// ---------------- Projection (layer 1): hrow[n][16]=h both heads; als/ald side ---
template<int FIN, int C>
__global__ void gat_proj(const void* __restrict__ xin,
                         const void* __restrict__ Wg,
                         const void* __restrict__ asg,
                         const void* __restrict__ adg,
                         float* __restrict__ hrow,
                         float* __restrict__ als,
                         float* __restrict__ ald,
                         int n, const int* __restrict__ flag) {
  const int isf = *flag;
  constexpr int FOUT = 2 * C;
  __shared__ float Ws[FIN * FOUT];
  __shared__ float as_s[FOUT], ad_s[FOUT];
  for (int i = threadIdx.x; i < FIN * FOUT; i += blockDim.x) Ws[i] = ldany(Wg, i, isf);
  if (threadIdx.x < FOUT) {
    as_s[threadIdx.x] = ldany(asg, threadIdx.x, isf);
    ad_s[threadIdx.x] = ldany(adg, threadIdx.x, isf);
  }
  __syncthreads();
  int nid = blockIdx.x * blockDim.x + threadIdx.x;
  if (nid >= n) return;

  float xr[FIN];
  #pragma unroll
  for (int i = 0; i < FIN; ++i) xr[i] = ldany(xin, (size_t)nid * FIN + i, isf);

  float hv[FOUT];
  #pragma unroll
  for (int j = 0; j < FOUT; ++j) hv[j] = 0.f;
  #pragma unroll
  for (int k = 0; k < FIN; ++k) {
    #pragma unroll
    for (int j = 0; j < FOUT; ++j) hv[j] += xr[k] * Ws[k * FOUT + j];
  }

  float* row = hrow + (size_t)nid * FOUT;
  #pragma unroll
  for (int j = 0; j < FOUT; ++j) row[j] = hv[j];

  #pragma unroll
  for (int hh = 0; hh < 2; ++hh) {
    float s = 0.f, dd = 0.f;
    #pragma unroll
    for (int c = 0; c < C; ++c) {
      s  += hv[hh * C + c] * as_s[hh * C + c];
      dd += hv[hh * C + c] * ad_s[hh * C + c];
    }
    als[(size_t)nid * 2 + hh] = s;
    ald[(size_t)nid * 2 + hh] = dd;
  }
}

// ---------------- Gather: 8 threads/node, both heads per thread, 2-edge batch ----
// hrow row = 2C floats (one 64B line for C=8, 32B for C=4). als/ald side tables.
template<int C, bool LAYER1>
__global__ __launch_bounds__(TB) void
gat_gather(const int* __restrict__ rowptr, const int* __restrict__ csr,
           const float* __restrict__ hrow, const float* __restrict__ als,
           const float* __restrict__ ald,
           const void* __restrict__ bias,
           const void* __restrict__ W2g, const void* __restrict__ as2g,
           const void* __restrict__ ad2g,
           float* __restrict__ hrow2, float* __restrict__ als2, float* __restrict__ ald2,
           void* __restrict__ outp, int n, const int* __restrict__ flag) {
  const int isf = *flag;
  constexpr int FOUT = 2 * C;
  constexpr int NV = FOUT / 4;          // float4s per row
  __shared__ float sb[FOUT];
  __shared__ float sv[LAYER1 ? 32 * 17 : 1];
  __shared__ float W2s[LAYER1 ? 128 : 1];
  __shared__ float as2s[LAYER1 ? 8 : 1], ad2s[LAYER1 ? 8 : 1];
  if (threadIdx.x < FOUT) sb[threadIdx.x] = ldany(bias, threadIdx.x, isf);
  if constexpr (LAYER1) {
    for (int i = threadIdx.x; i < 128; i += TB) W2s[i] = ldany(W2g, i, isf);
    if (threadIdx.x < 8) {
      as2s[threadIdx.x] = ldany(as2g, threadIdx.x, isf);
      ad2s[threadIdx.x] = ldany(ad2g, threadIdx.x, isf);
    }
  }
  __syncthreads();

  const int t = blockIdx.x * TB + threadIdx.x;
  const int half = t & 7, nid = t >> 3;
  const bool act = nid < n;
  int beg = 0, end = 0;
  float ald0 = 0.f, ald1 = 0.f;
  if (act) {
    beg = rowptr[nid];
    end = rowptr[nid + 1];
    float2 ad = ((const float2*)ald)[nid];
    ald0 = ad.x; ald1 = ad.y;
  }

  float acc[FOUT];
  #pragma unroll
  for (int c = 0; c < FOUT; ++c) acc[c] = 0.f;
  float z0 = 0.f, z1 = 0.f;

  int k = beg + half;
  for (; k + 8 < end; k += 16) {          // 2-edge batch: all loads in flight first
    int sA = csr[k], sB = csr[k + 8];
    const float4* rA = (const float4*)(hrow + (size_t)sA * FOUT);
    const float4* rB = (const float4*)(hrow + (size_t)sB * FOUT);
    float4 fA[NV], fB[NV];
    #pragma unroll
    for (int q = 0; q < NV; ++q) { fA[q] = rA[q]; fB[q] = rB[q]; }
    float2 aA = ((const float2*)als)[sA];
    float2 aB = ((const float2*)als)[sB];
    float lgA0 = aA.x + ald0, lgA1 = aA.y + ald1;
    float lgB0 = aB.x + ald0, lgB1 = aB.y + ald1;
    lgA0 = lgA0 > 0.f ? lgA0 : 0.2f * lgA0;
    lgA1 = lgA1 > 0.f ? lgA1 : 0.2f * lgA1;
    lgB0 = lgB0 > 0.f ? lgB0 : 0.2f * lgB0;
    lgB1 = lgB1 > 0.f ? lgB1 : 0.2f * lgB1;
    float wA0 = __expf(lgA0), wA1 = __expf(lgA1);
    float wB0 = __expf(lgB0), wB1 = __expf(lgB1);
    z0 += wA0 + wB0; z1 += wA1 + wB1;
    const float* hA = (const float*)fA;
    const float* hB = (const float*)fB;
    #pragma unroll
    for (int c = 0; c < C; ++c) {
      acc[c]     += wA0 * hA[c]     + wB0 * hB[c];
      acc[C + c] += wA1 * hA[C + c] + wB1 * hB[C + c];
    }
  }
  if (k < end) {                          // tail edge
    int sA = csr[k];
    const float4* rA = (const float4*)(hrow + (size_t)sA * FOUT);
    float4 fA[NV];
    #pragma unroll
    for (int q = 0; q < NV; ++q) fA[q] = rA[q];
    float2 aA = ((const float2*)als)[sA];
    float lgA0 = aA.x + ald0, lgA1 = aA.y + ald1;
    lgA0 = lgA0 > 0.f ? lgA0 : 0.2f * lgA0;
    lgA1 = lgA1 > 0.f ? lgA1 : 0.2f * lgA1;
    float wA0 = __expf(lgA0), wA1 = __expf(lgA1);
    z0 += wA0; z1 += wA1;
    const float* hA = (const float*)fA;
    #pragma unroll
    for (int c = 0; c < C; ++c) {
      acc[c]     += wA0 * hA[c];
      acc[C + c] += wA1 * hA[C + c];
    }
  }

  // combine the 8 lanes of this node
  #pragma unroll
  for (int off = 1; off < 8; off <<= 1) {
    z0 += __shfl_xor(z0, off);
    z1 += __shfl_xor(z1, off);
    #pragma unroll
    for (int c = 0; c < FOUT; ++c) acc[c] += __shfl_xor(acc[c], off);
  }
  float inv0 = 1.f / (z0 + 1e-16f);
  float inv1 = 1.f / (z1 + 1e-16f);

  if constexpr (LAYER1) {
    if (act && half == 0) {
      int ln = threadIdx.x >> 3;          // node slot in block (0..31)
      #pragma unroll
      for (int j = 0; j < FOUT; ++j) {
        float v = acc[j] * (j < C ? inv0 : inv1) + sb[j];
        v = v > 0.f ? v : expm1f(v);      // ELU
        sv[ln * 17 + j] = v;              // stride 17: no bank conflicts
      }
    }
    __syncthreads();
    int ln = threadIdx.x;
    if (ln < 32) {
      int nid2 = blockIdx.x * 32 + ln;
      if (nid2 < n) {
        float h2[8];
        #pragma unroll
        for (int j = 0; j < 8; ++j) h2[j] = 0.f;
        #pragma unroll
        for (int kk = 0; kk < 16; ++kk) {
          float v = sv[ln * 17 + kk];
          #pragma unroll
          for (int j = 0; j < 8; ++j) h2[j] += v * W2s[kk * 8 + j];
        }
        float* row2 = hrow2 + (size_t)nid2 * 8;
        #pragma unroll
        for (int j = 0; j < 8; ++j) row2[j] = h2[j];
        float s20 = 0.f, d20 = 0.f, s21 = 0.f, d21 = 0.f;
        #pragma unroll
        for (int c = 0; c < 4; ++c) {
          s20 += h2[c] * as2s[c];     d20 += h2[c] * ad2s[c];
          s21 += h2[4 + c] * as2s[4 + c]; d21 += h2[4 + c] * ad2s[4 + c];
        }
        ((float2*)als2)[nid2] = make_float2(s20, s21);
        ((float2*)ald2)[nid2] = make_float2(d20, d21);
      }
    }
  } else {
    if (act && half == 0) {
      #pragma unroll
      for (int j = 0; j < FOUT; ++j) {
        float v = acc[j] * (j < C ? inv0 : inv1) + sb[j];
        size_t oi = (size_t)nid * FOUT + j;
        if (isf) ((float*)outp)[oi] = v;
        else     ((__hip_bfloat16*)outp)[oi] = __float2bfloat16(v);
      }
    }
  }
}

extern "C" void kernel_launch(void* const* d_in, const int* in_sizes, int n_in,
                              void* d_out, int out_size, void* d_ws, size_t ws_size,
                              hipStream_t stream) {
  const void* x   = d_in[0];
  const int*  ei  = (const int*)d_in[1];
  const void* W1  = d_in[2];
  const void* as1 = d_in[3];
  const void* ad1 = d_in[4];
  const void* b1  = d_in[5];
  const void* W2  = d_in[6];
  const void* as2 = d_in[7];
  const void* ad2 = d_in[8];
  const void* b2  = d_in[9];

  const int n  = in_sizes[0] / 16;        // 100000
  const int E  = in_sizes[1] / 2;         // 3200000
  const int Et = E + n;                   // + self-loops
  const int NB = (n + BSZ - 1) >> BSH;    // 782 buckets

  // ---- workspace layout ----
  char* base = (char*)d_ws;
  int* flag   = (int*)base;               // 64 B
  int* gcnt   = (int*)(base + 64);        // NB+1
  int* gbase_ = gcnt + (NB + 1);          // NB+1
  int* gcur   = gbase_ + (NB + 1);        // NB
  int* rowptr = gcur + NB;                // n+1
  int* csr    = rowptr + (n + 1);         // Et (persists through both gathers)
  size_t off1 = 64 + sizeof(int) * ((size_t)(NB + 1) * 2 + NB + (size_t)(n + 1) + (size_t)Et);
  off1 = (off1 + 255) & ~(size_t)255;
  // Union region: packed (Et ints, dead after localsort) / layer-1 tables
  // (20n floats, written by gat_proj which runs after localsort).
  int*   packed = (int*)(base + off1);
  float* hrow1  = (float*)(base + off1);          // 16n: [h0(8), h1(8)] = one 64B line
  float* als1   = hrow1 + (size_t)16 * n;         // 2n
  float* ald1   = als1 + (size_t)2 * n;           // 2n
  size_t usz = sizeof(int) * (size_t)Et;
  size_t fsz = sizeof(float) * (size_t)20 * n;
  size_t off2 = off1 + (usz > fsz ? usz : fsz);
  off2 = (off2 + 255) & ~(size_t)255;
  float* hrow2 = (float*)(base + off2);           // 8n: [h0(4), h1(4)] = 32B row
  float* als2  = hrow2 + (size_t)8 * n;           // 2n
  float* ald2  = als2 + (size_t)2 * n;            // 2n

  const int nblk  = (n + TB - 1) / TB;
  const int EB    = (Et + CHUNK - 1) / CHUNK;
  const int gblk8 = (8 * n + TB - 1) / TB;        // 8 threads per node

  detect_dtype<<<1, 64, 0, stream>>>((const unsigned short*)x, flag);

  // ---- bucket counting sort -> dst-sorted CSR (once; shared by both layers) ----
  hipMemsetAsync(gcnt, 0, (size_t)(NB + 1) * sizeof(int), stream);
  k_bcount<<<EB, TBB, 0, stream>>>(ei, E, Et, NB, gcnt);
  k_bscan<<<1, 1024, 0, stream>>>(gcnt, gbase_, gcur, NB, Et);
  k_bscatter<<<EB, TBB, 0, stream>>>(ei, E, Et, NB, gcur, packed);
  k_localsort<<<NB, 512, 0, stream>>>(gbase_, packed, rowptr, csr, n, Et);

  // ---- Layer 1 proj (after localsort: hrow1 overlaps packed) ----
  gat_proj<16, 8><<<nblk, TB, 0, stream>>>(x, W1, as1, ad1, hrow1, als1, ald1, n, flag);

  // ---- Layer 1 gather + finalize + fused proj2 ----
  gat_gather<8, true><<<gblk8, TB, 0, stream>>>(rowptr, csr, hrow1, als1, ald1, b1,
                                                W2, as2, ad2, hrow2, als2, ald2,
                                                nullptr, n, flag);

  // ---- Layer 2 gather + finalize -> d_out ----
  gat_gather<4, false><<<gblk8, TB, 0, stream>>>(rowptr, csr, hrow2, als2, ald2, b2,
                                                 nullptr, nullptr, nullptr,
                                                 nullptr, nullptr, nullptr, d_out, n, flag);
}

// Round 8
// 186.471 us; speedup vs baseline: 3.8119x; 1.0942x over previous
//
#include <hip/hip_runtime.h>
#include <hip/hip_bf16.h>

#define TB 256
#define TBB 1024         // block size for edge count/scatter (occupancy!)
#define BSH 7            // 128 nodes per bucket
#define BSZ 128
#define CHUNK 16384      // edges per block in bucket count/scatter

// Load element i of p as float, where p is either f32 (isf32=1) or bf16 bits (isf32=0).
__device__ __forceinline__ float ldany(const void* __restrict__ p, size_t i, int isf32) {
  if (isf32) return ((const float*)p)[i];
  unsigned int u = ((const unsigned short*)p)[i];
  return __uint_as_float(u << 16);
}

// Detect input float dtype: bf16 N(0,1) exponent field <= ~130; f32 misread as bf16
// gives uniform-random exponent fields, max >> 160 over 256 samples.
__global__ void detect_dtype(const unsigned short* __restrict__ xb, int* __restrict__ flag) {
  int mx = 0;
  for (int i = threadIdx.x; i < 256; i += 64) { int e = (xb[i] >> 7) & 0xFF; mx = max(mx, e); }
  #pragma unroll
  for (int off = 32; off > 0; off >>= 1) mx = max(mx, __shfl_xor(mx, off));
  if (threadIdx.x == 0) *flag = (mx > 160) ? 1 : 0;   // 1 => inputs are float32
}

// ---------------- bucket counting sort (by dst >> BSH) ----------------
__global__ __launch_bounds__(TBB) void k_bcount(const int* __restrict__ ei, int E, int Et,
                                                int NB, int* __restrict__ gcnt) {
  __shared__ int lcnt[1024];
  for (int i = threadIdx.x; i < NB; i += TBB) lcnt[i] = 0;
  __syncthreads();
  long b0 = (long)blockIdx.x * CHUNK;
  int cnt = (int)(((long)Et - b0 < (long)CHUNK) ? ((long)Et - b0) : (long)CHUNK);
  for (int i = threadIdx.x * 4; i < cnt; i += TBB * 4) {
    long e = b0 + i;
    int rem = cnt - i;
    if (rem >= 4 && e + 3 < (long)E) {
      int4 d4 = *(const int4*)(ei + E + e);      // aligned: E%4==0, e%4==0
      atomicAdd(&lcnt[d4.x >> BSH], 1);
      atomicAdd(&lcnt[d4.y >> BSH], 1);
      atomicAdd(&lcnt[d4.z >> BSH], 1);
      atomicAdd(&lcnt[d4.w >> BSH], 1);
    } else {
      int m = rem < 4 ? rem : 4;
      for (int j = 0; j < m; ++j) {
        long ee = e + j;
        int d = (ee < E) ? ei[E + ee] : (int)(ee - E);
        atomicAdd(&lcnt[d >> BSH], 1);
      }
    }
  }
  __syncthreads();
  for (int i = threadIdx.x; i < NB; i += TBB) {
    int c = lcnt[i];
    if (c) atomicAdd(&gcnt[i], c);
  }
}

// Exclusive scan over NB (<=1024) bucket counts; init cursor; set gbase[NB]=Et.
__global__ void k_bscan(const int* __restrict__ gcnt, int* __restrict__ gbase,
                        int* __restrict__ gcur, int NB, int Et) {
  __shared__ int sh[1024];
  int tid = threadIdx.x;
  int v = (tid < NB) ? gcnt[tid] : 0;
  sh[tid] = v;
  __syncthreads();
  for (int off = 1; off < 1024; off <<= 1) {
    int t = (tid >= off) ? sh[tid - off] : 0;
    __syncthreads();
    sh[tid] += t;
    __syncthreads();
  }
  if (tid < NB) { int b = sh[tid] - v; gbase[tid] = b; gcur[tid] = b; }
  if (tid == 0) gbase[NB] = Et;
}

// Scatter packed edges ((dst&127)<<17 | src) into bucket-ordered array.
__global__ __launch_bounds__(TBB) void k_bscatter(const int* __restrict__ ei, int E, int Et,
                                                  int NB, int* __restrict__ gcur,
                                                  int* __restrict__ packed) {
  __shared__ int lcnt[1024];
  __shared__ int lbase[1024];
  for (int i = threadIdx.x; i < NB; i += TBB) lcnt[i] = 0;
  __syncthreads();
  long b0 = (long)blockIdx.x * CHUNK;
  int cnt = (int)(((long)Et - b0 < (long)CHUNK) ? ((long)Et - b0) : (long)CHUNK);
  for (int i = threadIdx.x * 4; i < cnt; i += TBB * 4) {
    long e = b0 + i;
    int rem = cnt - i;
    if (rem >= 4 && e + 3 < (long)E) {
      int4 d4 = *(const int4*)(ei + E + e);
      atomicAdd(&lcnt[d4.x >> BSH], 1);
      atomicAdd(&lcnt[d4.y >> BSH], 1);
      atomicAdd(&lcnt[d4.z >> BSH], 1);
      atomicAdd(&lcnt[d4.w >> BSH], 1);
    } else {
      int m = rem < 4 ? rem : 4;
      for (int j = 0; j < m; ++j) {
        long ee = e + j;
        int d = (ee < E) ? ei[E + ee] : (int)(ee - E);
        atomicAdd(&lcnt[d >> BSH], 1);
      }
    }
  }
  __syncthreads();
  for (int i = threadIdx.x; i < NB; i += TBB) {
    int c = lcnt[i];
    lbase[i] = c ? atomicAdd(&gcur[i], c) : 0;
  }
  __syncthreads();
  for (int i = threadIdx.x * 4; i < cnt; i += TBB * 4) {
    long e = b0 + i;
    int rem = cnt - i;
    if (rem >= 4 && e + 3 < (long)E) {
      int4 s4 = *(const int4*)(ei + e);
      int4 d4 = *(const int4*)(ei + E + e);
      int bk, pos;
      bk = d4.x >> BSH; pos = atomicAdd(&lbase[bk], 1); packed[pos] = ((d4.x & (BSZ-1)) << 17) | s4.x;
      bk = d4.y >> BSH; pos = atomicAdd(&lbase[bk], 1); packed[pos] = ((d4.y & (BSZ-1)) << 17) | s4.y;
      bk = d4.z >> BSH; pos = atomicAdd(&lbase[bk], 1); packed[pos] = ((d4.z & (BSZ-1)) << 17) | s4.z;
      bk = d4.w >> BSH; pos = atomicAdd(&lbase[bk], 1); packed[pos] = ((d4.w & (BSZ-1)) << 17) | s4.w;
    } else {
      int m = rem < 4 ? rem : 4;
      for (int j = 0; j < m; ++j) {
        long ee = e + j;
        int s, d;
        if (ee < E) { s = ei[ee]; d = ei[E + ee]; }
        else        { s = (int)(ee - E); d = s; }
        int bk = d >> BSH;
        int pos = atomicAdd(&lbase[bk], 1);
        packed[pos] = ((d & (BSZ - 1)) << 17) | s;
      }
    }
  }
}

// Local counting sort within each bucket -> full dst-sorted CSR + rowptr.
__global__ __launch_bounds__(512) void k_localsort(const int* __restrict__ gbase,
                                                   const int* __restrict__ packed,
                                                   int* __restrict__ rowptr,
                                                   int* __restrict__ csr,
                                                   int n, int Et) {
  __shared__ int lcnt[BSZ], lbase[BSZ], sh[BSZ];
  const int b = blockIdx.x;
  const int node0 = b << BSH;
  const int tid = threadIdx.x;
  if (tid < BSZ) lcnt[tid] = 0;
  __syncthreads();
  const int beg = gbase[b], end = gbase[b + 1];
  for (int k = beg + tid; k < end; k += 512)
    atomicAdd(&lcnt[packed[k] >> 17], 1);
  __syncthreads();
  int v = (tid < BSZ) ? lcnt[tid] : 0;
  if (tid < BSZ) sh[tid] = v;
  __syncthreads();
  for (int off = 1; off < BSZ; off <<= 1) {
    int t = (tid < BSZ && tid >= off) ? sh[tid - off] : 0;
    __syncthreads();
    if (tid < BSZ) sh[tid] += t;
    __syncthreads();
  }
  if (tid < BSZ) lbase[tid] = sh[tid] - v;
  __syncthreads();
  const int nn = min(BSZ, n - node0);
  if (tid < nn) rowptr[node0 + tid] = beg + lbase[tid];
  if (b == 0 && tid == 0) rowptr[n] = Et;
  for (int k = beg + tid; k < end; k += 512) {
    int p = packed[k];
    int dl = p >> 17;
    int pos = beg + atomicAdd(&lbase[dl], 1);
    csr[pos] = p & 0x1FFFF;
  }
}

// ---------------- Projection (layer 1): hrow[n][16]=h both heads; als/ald side ---
template<int FIN, int C>
__global__ void gat_proj(const void* __restrict__ xin,
                         const void* __restrict__ Wg,
                         const void* __restrict__ asg,
                         const void* __restrict__ adg,
                         float* __restrict__ hrow,
                         float* __restrict__ als,
                         float* __restrict__ ald,
                         int n, const int* __restrict__ flag) {
  const int isf = *flag;
  constexpr int FOUT = 2 * C;
  __shared__ float Ws[FIN * FOUT];
  __shared__ float as_s[FOUT], ad_s[FOUT];
  for (int i = threadIdx.x; i < FIN * FOUT; i += blockDim.x) Ws[i] = ldany(Wg, i, isf);
  if (threadIdx.x < FOUT) {
    as_s[threadIdx.x] = ldany(asg, threadIdx.x, isf);
    ad_s[threadIdx.x] = ldany(adg, threadIdx.x, isf);
  }
  __syncthreads();
  int nid = blockIdx.x * blockDim.x + threadIdx.x;
  if (nid >= n) return;

  float xr[FIN];
  #pragma unroll
  for (int i = 0; i < FIN; ++i) xr[i] = ldany(xin, (size_t)nid * FIN + i, isf);

  float hv[FOUT];
  #pragma unroll
  for (int j = 0; j < FOUT; ++j) hv[j] = 0.f;
  #pragma unroll
  for (int k = 0; k < FIN; ++k) {
    #pragma unroll
    for (int j = 0; j < FOUT; ++j) hv[j] += xr[k] * Ws[k * FOUT + j];
  }

  float* row = hrow + (size_t)nid * FOUT;
  #pragma unroll
  for (int j = 0; j < FOUT; ++j) row[j] = hv[j];

  #pragma unroll
  for (int hh = 0; hh < 2; ++hh) {
    float s = 0.f, dd = 0.f;
    #pragma unroll
    for (int c = 0; c < C; ++c) {
      s  += hv[hh * C + c] * as_s[hh * C + c];
      dd += hv[hh * C + c] * ad_s[hh * C + c];
    }
    als[(size_t)nid * 2 + hh] = s;
    ald[(size_t)nid * 2 + hh] = dd;
  }
}

// ---------------- Cooperative gather: 16 lanes/node, LPE lanes/edge -------------
// LPE = FOUT/4 lanes cooperatively load one source row (1 float4 each); SLOTS =
// 16/LPE edges in flight per node. csr index software-pipelined. Combine via
// shfl_xor over slot bits (each lane keeps its own output quarter q).
template<int C, bool LAYER1>
__global__ __launch_bounds__(TB) void
gat_gather(const int* __restrict__ rowptr, const int* __restrict__ csr,
           const float* __restrict__ hrow, const float* __restrict__ als,
           const float* __restrict__ ald,
           const void* __restrict__ bias,
           const void* __restrict__ W2g, const void* __restrict__ as2g,
           const void* __restrict__ ad2g,
           float* __restrict__ hrow2, float* __restrict__ als2, float* __restrict__ ald2,
           void* __restrict__ outp, int n, const int* __restrict__ flag) {
  const int isf = *flag;
  constexpr int FOUT  = 2 * C;
  constexpr int LPE   = FOUT / 4;    // lanes per edge: L1=4, L2=2
  constexpr int SLOTS = 16 / LPE;    // edge slots per node: L1=4, L2=8
  __shared__ float sb[FOUT];
  __shared__ float sv[LAYER1 ? 16 * 17 : 1];   // 16 nodes/block, stride 17
  __shared__ float W2s[LAYER1 ? 128 : 1];
  __shared__ float as2s[LAYER1 ? 8 : 1], ad2s[LAYER1 ? 8 : 1];
  if (threadIdx.x < FOUT) sb[threadIdx.x] = ldany(bias, threadIdx.x, isf);
  if constexpr (LAYER1) {
    for (int i = threadIdx.x; i < 128; i += TB) W2s[i] = ldany(W2g, i, isf);
    if (threadIdx.x < 8) {
      as2s[threadIdx.x] = ldany(as2g, threadIdx.x, isf);
      ad2s[threadIdx.x] = ldany(ad2g, threadIdx.x, isf);
    }
  }
  __syncthreads();

  const int t = blockIdx.x * TB + threadIdx.x;
  const int sub = t & 15, nid = t >> 4;
  const int slot = sub / LPE, q = sub % LPE;
  const int hq = (4 * q) / C;        // head owning this lane's quarter
  const bool act = nid < n;
  int beg = 0, end = 0;
  float aldv = 0.f;
  if (act) {
    beg = rowptr[nid];
    end = rowptr[nid + 1];
    aldv = ald[(size_t)nid * 2 + hq];
  }

  float a0 = 0.f, a1 = 0.f, a2 = 0.f, a3 = 0.f, z = 0.f;
  int k = beg + slot;
  int s = (k < end) ? csr[k] : 0;
  while (k < end) {
    int kn = k + SLOTS;
    int sn = (kn < end) ? csr[kn] : 0;           // prefetch next edge index
    float4 f4 = ((const float4*)(hrow + (size_t)s * FOUT))[q];
    float alsv = als[(size_t)s * 2 + hq];
    float lg = alsv + aldv;
    lg = lg > 0.f ? lg : 0.2f * lg;              // leaky_relu slope 0.2
    float w = __expf(lg);
    z += w;
    a0 += w * f4.x; a1 += w * f4.y; a2 += w * f4.z; a3 += w * f4.w;
    k = kn; s = sn;
  }

  #pragma unroll
  for (int off = LPE; off < 16; off <<= 1) {     // combine slots, keep quarter q
    z  += __shfl_xor(z, off);
    a0 += __shfl_xor(a0, off); a1 += __shfl_xor(a1, off);
    a2 += __shfl_xor(a2, off); a3 += __shfl_xor(a3, off);
  }
  float inv = 1.f / (z + 1e-16f);
  float v0 = a0 * inv + sb[4 * q + 0];
  float v1 = a1 * inv + sb[4 * q + 1];
  float v2 = a2 * inv + sb[4 * q + 2];
  float v3 = a3 * inv + sb[4 * q + 3];

  if constexpr (LAYER1) {
    if (act && sub < LPE) {                      // slot 0 lanes own the result
      int ns = threadIdx.x >> 4;
      v0 = v0 > 0.f ? v0 : expm1f(v0);           // ELU
      v1 = v1 > 0.f ? v1 : expm1f(v1);
      v2 = v2 > 0.f ? v2 : expm1f(v2);
      v3 = v3 > 0.f ? v3 : expm1f(v3);
      float* p = &sv[ns * 17 + 4 * q];
      p[0] = v0; p[1] = v1; p[2] = v2; p[3] = v3;
    }
    __syncthreads();
    if (threadIdx.x < 16) {
      int nid2 = blockIdx.x * 16 + threadIdx.x;
      if (nid2 < n) {
        float h2[8];
        #pragma unroll
        for (int j = 0; j < 8; ++j) h2[j] = 0.f;
        #pragma unroll
        for (int kk = 0; kk < 16; ++kk) {
          float v = sv[threadIdx.x * 17 + kk];
          #pragma unroll
          for (int j = 0; j < 8; ++j) h2[j] += v * W2s[kk * 8 + j];
        }
        float* row2 = hrow2 + (size_t)nid2 * 8;
        ((float4*)row2)[0] = make_float4(h2[0], h2[1], h2[2], h2[3]);
        ((float4*)row2)[1] = make_float4(h2[4], h2[5], h2[6], h2[7]);
        float s20 = 0.f, d20 = 0.f, s21 = 0.f, d21 = 0.f;
        #pragma unroll
        for (int c = 0; c < 4; ++c) {
          s20 += h2[c] * as2s[c];         d20 += h2[c] * ad2s[c];
          s21 += h2[4 + c] * as2s[4 + c]; d21 += h2[4 + c] * ad2s[4 + c];
        }
        ((float2*)als2)[nid2] = make_float2(s20, s21);
        ((float2*)ald2)[nid2] = make_float2(d20, d21);
      }
    }
  } else {
    if (act && sub < LPE) {
      if (isf) {
        ((float4*)outp)[(size_t)nid * 2 + q] = make_float4(v0, v1, v2, v3);
      } else {
        __hip_bfloat16 b0 = __float2bfloat16(v0), b1 = __float2bfloat16(v1);
        __hip_bfloat16 b2 = __float2bfloat16(v2), b3 = __float2bfloat16(v3);
        unsigned short u0, u1, u2, u3;
        __builtin_memcpy(&u0, &b0, 2); __builtin_memcpy(&u1, &b1, 2);
        __builtin_memcpy(&u2, &b2, 2); __builtin_memcpy(&u3, &b3, 2);
        ((ushort4*)outp)[(size_t)nid * 2 + q] = make_ushort4(u0, u1, u2, u3);
      }
    }
  }
}

extern "C" void kernel_launch(void* const* d_in, const int* in_sizes, int n_in,
                              void* d_out, int out_size, void* d_ws, size_t ws_size,
                              hipStream_t stream) {
  const void* x   = d_in[0];
  const int*  ei  = (const int*)d_in[1];
  const void* W1  = d_in[2];
  const void* as1 = d_in[3];
  const void* ad1 = d_in[4];
  const void* b1  = d_in[5];
  const void* W2  = d_in[6];
  const void* as2 = d_in[7];
  const void* ad2 = d_in[8];
  const void* b2  = d_in[9];

  const int n  = in_sizes[0] / 16;        // 100000
  const int E  = in_sizes[1] / 2;         // 3200000
  const int Et = E + n;                   // + self-loops
  const int NB = (n + BSZ - 1) >> BSH;    // 782 buckets

  // ---- workspace layout ----
  char* base = (char*)d_ws;
  int* flag   = (int*)base;               // 64 B
  int* gcnt   = (int*)(base + 64);        // NB+1
  int* gbase_ = gcnt + (NB + 1);          // NB+1
  int* gcur   = gbase_ + (NB + 1);        // NB
  int* rowptr = gcur + NB;                // n+1
  int* csr    = rowptr + (n + 1);         // Et (persists through both gathers)
  size_t off1 = 64 + sizeof(int) * ((size_t)(NB + 1) * 2 + NB + (size_t)(n + 1) + (size_t)Et);
  off1 = (off1 + 255) & ~(size_t)255;
  // Union region: packed (Et ints, dead after localsort) / layer-1 tables
  // (20n floats, written by gat_proj which runs after localsort).
  int*   packed = (int*)(base + off1);
  float* hrow1  = (float*)(base + off1);          // 16n: [h0(8), h1(8)] = one 64B line
  float* als1   = hrow1 + (size_t)16 * n;         // 2n
  float* ald1   = als1 + (size_t)2 * n;           // 2n
  size_t usz = sizeof(int) * (size_t)Et;
  size_t fsz = sizeof(float) * (size_t)20 * n;
  size_t off2 = off1 + (usz > fsz ? usz : fsz);
  off2 = (off2 + 255) & ~(size_t)255;
  float* hrow2 = (float*)(base + off2);           // 8n: [h0(4), h1(4)] = 32B row
  float* als2  = hrow2 + (size_t)8 * n;           // 2n
  float* ald2  = als2 + (size_t)2 * n;            // 2n

  const int nblk   = (n + TB - 1) / TB;
  const int EB     = (Et + CHUNK - 1) / CHUNK;
  const int gblk16 = (16 * n + TB - 1) / TB;      // 16 threads per node

  detect_dtype<<<1, 64, 0, stream>>>((const unsigned short*)x, flag);

  // ---- bucket counting sort -> dst-sorted CSR (once; shared by both layers) ----
  hipMemsetAsync(gcnt, 0, (size_t)(NB + 1) * sizeof(int), stream);
  k_bcount<<<EB, TBB, 0, stream>>>(ei, E, Et, NB, gcnt);
  k_bscan<<<1, 1024, 0, stream>>>(gcnt, gbase_, gcur, NB, Et);
  k_bscatter<<<EB, TBB, 0, stream>>>(ei, E, Et, NB, gcur, packed);
  k_localsort<<<NB, 512, 0, stream>>>(gbase_, packed, rowptr, csr, n, Et);

  // ---- Layer 1 proj (after localsort: hrow1 overlaps packed) ----
  gat_proj<16, 8><<<nblk, TB, 0, stream>>>(x, W1, as1, ad1, hrow1, als1, ald1, n, flag);

  // ---- Layer 1 gather + finalize + fused proj2 ----
  gat_gather<8, true><<<gblk16, TB, 0, stream>>>(rowptr, csr, hrow1, als1, ald1, b1,
                                                 W2, as2, ad2, hrow2, als2, ald2,
                                                 nullptr, n, flag);

  // ---- Layer 2 gather + finalize -> d_out ----
  gat_gather<4, false><<<gblk16, TB, 0, stream>>>(rowptr, csr, hrow2, als2, ald2, b2,
                                                  nullptr, nullptr, nullptr,
                                                  nullptr, nullptr, nullptr, d_out, n, flag);
}

// Round 9
// 166.677 us; speedup vs baseline: 4.2646x; 1.1188x over previous
//
#include <hip/hip_runtime.h>
#include <hip/hip_bf16.h>

#define TB 256
#define TBB 1024         // block size for edge count/scatter (occupancy!)
#define BSH 7            // 128 nodes per bucket
#define BSZ 128
#define CHUNK 16384      // edges per block in bucket count/scatter

// Load element i of p as float, where p is either f32 (isf32=1) or bf16 bits (isf32=0).
__device__ __forceinline__ float ldany(const void* __restrict__ p, size_t i, int isf32) {
  if (isf32) return ((const float*)p)[i];
  unsigned int u = ((const unsigned short*)p)[i];
  return __uint_as_float(u << 16);
}

// Pack two f32 into two bf16 (round-to-nearest-even): [lo | hi<<16].
__device__ __forceinline__ unsigned f2bf2(float lo, float hi) {
  unsigned ul = __float_as_uint(lo), uh = __float_as_uint(hi);
  ul += 0x7FFFu + ((ul >> 16) & 1u);
  uh += 0x7FFFu + ((uh >> 16) & 1u);
  return (ul >> 16) | (uh & 0xFFFF0000u);
}
__device__ __forceinline__ float bf_lo(unsigned u) { return __uint_as_float(u << 16); }
__device__ __forceinline__ float bf_hi(unsigned u) { return __uint_as_float(u & 0xFFFF0000u); }

// Detect input float dtype: bf16 N(0,1) exponent field <= ~130; f32 misread as bf16
// gives uniform-random exponent fields, max >> 160 over 256 samples.
__global__ void detect_dtype(const unsigned short* __restrict__ xb, int* __restrict__ flag) {
  int mx = 0;
  for (int i = threadIdx.x; i < 256; i += 64) { int e = (xb[i] >> 7) & 0xFF; mx = max(mx, e); }
  #pragma unroll
  for (int off = 32; off > 0; off >>= 1) mx = max(mx, __shfl_xor(mx, off));
  if (threadIdx.x == 0) *flag = (mx > 160) ? 1 : 0;   // 1 => inputs are float32
}

// ---------------- bucket counting sort (by dst >> BSH) ----------------
__global__ __launch_bounds__(TBB) void k_bcount(const int* __restrict__ ei, int E, int Et,
                                                int NB, int* __restrict__ gcnt) {
  __shared__ int lcnt[1024];
  for (int i = threadIdx.x; i < NB; i += TBB) lcnt[i] = 0;
  __syncthreads();
  long b0 = (long)blockIdx.x * CHUNK;
  int cnt = (int)(((long)Et - b0 < (long)CHUNK) ? ((long)Et - b0) : (long)CHUNK);
  for (int i = threadIdx.x * 4; i < cnt; i += TBB * 4) {
    long e = b0 + i;
    int rem = cnt - i;
    if (rem >= 4 && e + 3 < (long)E) {
      int4 d4 = *(const int4*)(ei + E + e);      // aligned: E%4==0, e%4==0
      atomicAdd(&lcnt[d4.x >> BSH], 1);
      atomicAdd(&lcnt[d4.y >> BSH], 1);
      atomicAdd(&lcnt[d4.z >> BSH], 1);
      atomicAdd(&lcnt[d4.w >> BSH], 1);
    } else {
      int m = rem < 4 ? rem : 4;
      for (int j = 0; j < m; ++j) {
        long ee = e + j;
        int d = (ee < E) ? ei[E + ee] : (int)(ee - E);
        atomicAdd(&lcnt[d >> BSH], 1);
      }
    }
  }
  __syncthreads();
  for (int i = threadIdx.x; i < NB; i += TBB) {
    int c = lcnt[i];
    if (c) atomicAdd(&gcnt[i], c);
  }
}

// Exclusive scan over NB (<=1024) bucket counts; init cursor; set gbase[NB]=Et.
__global__ void k_bscan(const int* __restrict__ gcnt, int* __restrict__ gbase,
                        int* __restrict__ gcur, int NB, int Et) {
  __shared__ int sh[1024];
  int tid = threadIdx.x;
  int v = (tid < NB) ? gcnt[tid] : 0;
  sh[tid] = v;
  __syncthreads();
  for (int off = 1; off < 1024; off <<= 1) {
    int t = (tid >= off) ? sh[tid - off] : 0;
    __syncthreads();
    sh[tid] += t;
    __syncthreads();
  }
  if (tid < NB) { int b = sh[tid] - v; gbase[tid] = b; gcur[tid] = b; }
  if (tid == 0) gbase[NB] = Et;
}

// Scatter packed edges ((dst&127)<<17 | src) into bucket-ordered array.
__global__ __launch_bounds__(TBB) void k_bscatter(const int* __restrict__ ei, int E, int Et,
                                                  int NB, int* __restrict__ gcur,
                                                  int* __restrict__ packed) {
  __shared__ int lcnt[1024];
  __shared__ int lbase[1024];
  for (int i = threadIdx.x; i < NB; i += TBB) lcnt[i] = 0;
  __syncthreads();
  long b0 = (long)blockIdx.x * CHUNK;
  int cnt = (int)(((long)Et - b0 < (long)CHUNK) ? ((long)Et - b0) : (long)CHUNK);
  for (int i = threadIdx.x * 4; i < cnt; i += TBB * 4) {
    long e = b0 + i;
    int rem = cnt - i;
    if (rem >= 4 && e + 3 < (long)E) {
      int4 d4 = *(const int4*)(ei + E + e);
      atomicAdd(&lcnt[d4.x >> BSH], 1);
      atomicAdd(&lcnt[d4.y >> BSH], 1);
      atomicAdd(&lcnt[d4.z >> BSH], 1);
      atomicAdd(&lcnt[d4.w >> BSH], 1);
    } else {
      int m = rem < 4 ? rem : 4;
      for (int j = 0; j < m; ++j) {
        long ee = e + j;
        int d = (ee < E) ? ei[E + ee] : (int)(ee - E);
        atomicAdd(&lcnt[d >> BSH], 1);
      }
    }
  }
  __syncthreads();
  for (int i = threadIdx.x; i < NB; i += TBB) {
    int c = lcnt[i];
    lbase[i] = c ? atomicAdd(&gcur[i], c) : 0;
  }
  __syncthreads();
  for (int i = threadIdx.x * 4; i < cnt; i += TBB * 4) {
    long e = b0 + i;
    int rem = cnt - i;
    if (rem >= 4 && e + 3 < (long)E) {
      int4 s4 = *(const int4*)(ei + e);
      int4 d4 = *(const int4*)(ei + E + e);
      int bk, pos;
      bk = d4.x >> BSH; pos = atomicAdd(&lbase[bk], 1); packed[pos] = ((d4.x & (BSZ-1)) << 17) | s4.x;
      bk = d4.y >> BSH; pos = atomicAdd(&lbase[bk], 1); packed[pos] = ((d4.y & (BSZ-1)) << 17) | s4.y;
      bk = d4.z >> BSH; pos = atomicAdd(&lbase[bk], 1); packed[pos] = ((d4.z & (BSZ-1)) << 17) | s4.z;
      bk = d4.w >> BSH; pos = atomicAdd(&lbase[bk], 1); packed[pos] = ((d4.w & (BSZ-1)) << 17) | s4.w;
    } else {
      int m = rem < 4 ? rem : 4;
      for (int j = 0; j < m; ++j) {
        long ee = e + j;
        int s, d;
        if (ee < E) { s = ei[ee]; d = ei[E + ee]; }
        else        { s = (int)(ee - E); d = s; }
        int bk = d >> BSH;
        int pos = atomicAdd(&lbase[bk], 1);
        packed[pos] = ((d & (BSZ - 1)) << 17) | s;
      }
    }
  }
}

// Local counting sort within each bucket -> full dst-sorted CSR + rowptr.
__global__ __launch_bounds__(512) void k_localsort(const int* __restrict__ gbase,
                                                   const int* __restrict__ packed,
                                                   int* __restrict__ rowptr,
                                                   int* __restrict__ csr,
                                                   int n, int Et) {
  __shared__ int lcnt[BSZ], lbase[BSZ], sh[BSZ];
  const int b = blockIdx.x;
  const int node0 = b << BSH;
  const int tid = threadIdx.x;
  if (tid < BSZ) lcnt[tid] = 0;
  __syncthreads();
  const int beg = gbase[b], end = gbase[b + 1];
  for (int k = beg + tid; k < end; k += 512)
    atomicAdd(&lcnt[packed[k] >> 17], 1);
  __syncthreads();
  int v = (tid < BSZ) ? lcnt[tid] : 0;
  if (tid < BSZ) sh[tid] = v;
  __syncthreads();
  for (int off = 1; off < BSZ; off <<= 1) {
    int t = (tid < BSZ && tid >= off) ? sh[tid - off] : 0;
    __syncthreads();
    if (tid < BSZ) sh[tid] += t;
    __syncthreads();
  }
  if (tid < BSZ) lbase[tid] = sh[tid] - v;
  __syncthreads();
  const int nn = min(BSZ, n - node0);
  if (tid < nn) rowptr[node0 + tid] = beg + lbase[tid];
  if (b == 0 && tid == 0) rowptr[n] = Et;
  for (int k = beg + tid; k < end; k += 512) {
    int p = packed[k];
    int dl = p >> 17;
    int pos = beg + atomicAdd(&lbase[dl], 1);
    csr[pos] = p & 0x1FFFF;
  }
}

// ---------------- Projection (layer 1): bf16 tables hb1[n][16], ab1[n]; f32 ald --
__global__ void gat_proj(const void* __restrict__ xin,
                         const void* __restrict__ Wg,
                         const void* __restrict__ asg,
                         const void* __restrict__ adg,
                         unsigned* __restrict__ hb,     // n x 8 uints (16 bf16)
                         unsigned* __restrict__ ab,     // n x (2 bf16 als)
                         float* __restrict__ ald,       // n x 2 f32
                         int n, const int* __restrict__ flag) {
  const int isf = *flag;
  __shared__ float Ws[16 * 16];
  __shared__ float as_s[16], ad_s[16];
  for (int i = threadIdx.x; i < 256; i += blockDim.x) Ws[i] = ldany(Wg, i, isf);
  if (threadIdx.x < 16) {
    as_s[threadIdx.x] = ldany(asg, threadIdx.x, isf);
    ad_s[threadIdx.x] = ldany(adg, threadIdx.x, isf);
  }
  __syncthreads();
  int nid = blockIdx.x * blockDim.x + threadIdx.x;
  if (nid >= n) return;

  float xr[16];
  #pragma unroll
  for (int i = 0; i < 16; ++i) xr[i] = ldany(xin, (size_t)nid * 16 + i, isf);

  float hv[16];
  #pragma unroll
  for (int j = 0; j < 16; ++j) hv[j] = 0.f;
  #pragma unroll
  for (int k = 0; k < 16; ++k) {
    #pragma unroll
    for (int j = 0; j < 16; ++j) hv[j] += xr[k] * Ws[k * 16 + j];
  }

  unsigned* row = hb + (size_t)nid * 8;
  ((uint4*)row)[0] = make_uint4(f2bf2(hv[0], hv[1]),  f2bf2(hv[2], hv[3]),
                                f2bf2(hv[4], hv[5]),  f2bf2(hv[6], hv[7]));
  ((uint4*)row)[1] = make_uint4(f2bf2(hv[8], hv[9]),  f2bf2(hv[10], hv[11]),
                                f2bf2(hv[12], hv[13]), f2bf2(hv[14], hv[15]));

  float s0 = 0.f, d0 = 0.f, s1 = 0.f, d1 = 0.f;
  #pragma unroll
  for (int c = 0; c < 8; ++c) {
    s0 += hv[c] * as_s[c];         d0 += hv[c] * ad_s[c];
    s1 += hv[8 + c] * as_s[8 + c]; d1 += hv[8 + c] * ad_s[8 + c];
  }
  ab[nid] = f2bf2(s0, s1);
  ((float2*)ald)[nid] = make_float2(d0, d1);
}

// ---------------- Layer-1 gather: 16 lanes/node, 2 lanes/edge (16B bf16 each) ----
// Fused: softmax-normalize + bias + ELU + proj2(W2,att2) -> layer-2 bf16 tables.
__global__ __launch_bounds__(TB) void
gat_gather1(const int* __restrict__ rowptr, const int* __restrict__ csr,
            const unsigned* __restrict__ hb, const unsigned* __restrict__ ab,
            const float* __restrict__ ald,
            const void* __restrict__ bias,
            const void* __restrict__ W2g, const void* __restrict__ as2g,
            const void* __restrict__ ad2g,
            unsigned* __restrict__ hb2, unsigned* __restrict__ ab2,
            float* __restrict__ ald2,
            int n, const int* __restrict__ flag) {
  const int isf = *flag;
  __shared__ float sb[16];
  __shared__ float sv[16 * 17];
  __shared__ float W2s[128];
  __shared__ float as2s[8], ad2s[8];
  if (threadIdx.x < 16) sb[threadIdx.x] = ldany(bias, threadIdx.x, isf);
  for (int i = threadIdx.x; i < 128; i += TB) W2s[i] = ldany(W2g, i, isf);
  if (threadIdx.x < 8) {
    as2s[threadIdx.x] = ldany(as2g, threadIdx.x, isf);
    ad2s[threadIdx.x] = ldany(ad2g, threadIdx.x, isf);
  }
  __syncthreads();

  const int t = blockIdx.x * TB + threadIdx.x;
  const int sub = t & 15, nid = t >> 4;
  const int slot = sub >> 1, hq = sub & 1;      // 8 edge slots x 2 head-lanes
  const bool act = nid < n;
  int beg = 0, end = 0;
  float aldv = 0.f;
  if (act) {
    beg = rowptr[nid];
    end = rowptr[nid + 1];
    aldv = ald[(size_t)nid * 2 + hq];
  }

  float acc[8];
  #pragma unroll
  for (int c = 0; c < 8; ++c) acc[c] = 0.f;
  float z = 0.f;

  int k = beg + slot;
  int s = (k < end) ? csr[k] : 0;
  while (k < end) {
    int kn = k + 8;
    int sn = (kn < end) ? csr[kn] : 0;          // prefetch next edge index
    uint4 u = *(const uint4*)(hb + (size_t)s * 8 + hq * 4);   // this head's 8 bf16
    unsigned a = ab[s];
    float alsv = hq ? bf_hi(a) : bf_lo(a);
    float lg = alsv + aldv;
    lg = lg > 0.f ? lg : 0.2f * lg;             // leaky_relu slope 0.2
    float w = __expf(lg);
    z += w;
    acc[0] += w * bf_lo(u.x); acc[1] += w * bf_hi(u.x);
    acc[2] += w * bf_lo(u.y); acc[3] += w * bf_hi(u.y);
    acc[4] += w * bf_lo(u.z); acc[5] += w * bf_hi(u.z);
    acc[6] += w * bf_lo(u.w); acc[7] += w * bf_hi(u.w);
    k = kn; s = sn;
  }

  #pragma unroll
  for (int off = 2; off < 16; off <<= 1) {      // combine slots, keep head bit
    z += __shfl_xor(z, off);
    #pragma unroll
    for (int c = 0; c < 8; ++c) acc[c] += __shfl_xor(acc[c], off);
  }
  float inv = 1.f / (z + 1e-16f);

  if (act && slot == 0) {                       // lanes sub=0(head0),1(head1)
    int ns = threadIdx.x >> 4;
    #pragma unroll
    for (int c = 0; c < 8; ++c) {
      float v = acc[c] * inv + sb[hq * 8 + c];
      v = v > 0.f ? v : expm1f(v);              // ELU
      sv[ns * 17 + hq * 8 + c] = v;
    }
  }
  __syncthreads();
  if (threadIdx.x < 16) {
    int nid2 = blockIdx.x * 16 + threadIdx.x;
    if (nid2 < n) {
      float h2[8];
      #pragma unroll
      for (int j = 0; j < 8; ++j) h2[j] = 0.f;
      #pragma unroll
      for (int kk = 0; kk < 16; ++kk) {
        float v = sv[threadIdx.x * 17 + kk];
        #pragma unroll
        for (int j = 0; j < 8; ++j) h2[j] += v * W2s[kk * 8 + j];
      }
      ((uint4*)(hb2 + (size_t)nid2 * 4))[0] =
          make_uint4(f2bf2(h2[0], h2[1]), f2bf2(h2[2], h2[3]),
                     f2bf2(h2[4], h2[5]), f2bf2(h2[6], h2[7]));
      float s20 = 0.f, d20 = 0.f, s21 = 0.f, d21 = 0.f;
      #pragma unroll
      for (int c = 0; c < 4; ++c) {
        s20 += h2[c] * as2s[c];         d20 += h2[c] * ad2s[c];
        s21 += h2[4 + c] * as2s[4 + c]; d21 += h2[4 + c] * ad2s[4 + c];
      }
      ab2[nid2] = f2bf2(s20, s21);
      ((float2*)ald2)[nid2] = make_float2(d20, d21);
    }
  }
}

// ---------------- Layer-2 gather: 16 lanes/node, 1 lane/edge (16B = both heads) --
__global__ __launch_bounds__(TB) void
gat_gather2(const int* __restrict__ rowptr, const int* __restrict__ csr,
            const unsigned* __restrict__ hb2, const unsigned* __restrict__ ab2,
            const float* __restrict__ ald2,
            const void* __restrict__ bias,
            void* __restrict__ outp, int n, const int* __restrict__ flag) {
  const int isf = *flag;
  __shared__ float sb[8];
  if (threadIdx.x < 8) sb[threadIdx.x] = ldany(bias, threadIdx.x, isf);
  __syncthreads();

  const int t = blockIdx.x * TB + threadIdx.x;
  const int sub = t & 15, nid = t >> 4;
  const bool act = nid < n;
  int beg = 0, end = 0;
  float ald0 = 0.f, ald1 = 0.f;
  if (act) {
    beg = rowptr[nid];
    end = rowptr[nid + 1];
    float2 ad = ((const float2*)ald2)[nid];
    ald0 = ad.x; ald1 = ad.y;
  }

  float acc[8];
  #pragma unroll
  for (int c = 0; c < 8; ++c) acc[c] = 0.f;
  float z0 = 0.f, z1 = 0.f;

  int k = beg + sub;
  int s = (k < end) ? csr[k] : 0;
  while (k < end) {
    int kn = k + 16;
    int sn = (kn < end) ? csr[kn] : 0;
    uint4 u = *(const uint4*)(hb2 + (size_t)s * 4);   // both heads' 8 bf16
    unsigned a = ab2[s];
    float lg0 = bf_lo(a) + ald0, lg1 = bf_hi(a) + ald1;
    lg0 = lg0 > 0.f ? lg0 : 0.2f * lg0;
    lg1 = lg1 > 0.f ? lg1 : 0.2f * lg1;
    float w0 = __expf(lg0), w1 = __expf(lg1);
    z0 += w0; z1 += w1;
    acc[0] += w0 * bf_lo(u.x); acc[1] += w0 * bf_hi(u.x);
    acc[2] += w0 * bf_lo(u.y); acc[3] += w0 * bf_hi(u.y);
    acc[4] += w1 * bf_lo(u.z); acc[5] += w1 * bf_hi(u.z);
    acc[6] += w1 * bf_lo(u.w); acc[7] += w1 * bf_hi(u.w);
    k = kn; s = sn;
  }

  #pragma unroll
  for (int off = 1; off < 16; off <<= 1) {
    z0 += __shfl_xor(z0, off); z1 += __shfl_xor(z1, off);
    #pragma unroll
    for (int c = 0; c < 8; ++c) acc[c] += __shfl_xor(acc[c], off);
  }

  if (act && sub == 0) {
    float inv0 = 1.f / (z0 + 1e-16f), inv1 = 1.f / (z1 + 1e-16f);
    float v[8];
    #pragma unroll
    for (int c = 0; c < 8; ++c) v[c] = acc[c] * (c < 4 ? inv0 : inv1) + sb[c];
    if (isf) {
      ((float4*)outp)[(size_t)nid * 2 + 0] = make_float4(v[0], v[1], v[2], v[3]);
      ((float4*)outp)[(size_t)nid * 2 + 1] = make_float4(v[4], v[5], v[6], v[7]);
    } else {
      ((uint4*)outp)[nid] = make_uint4(f2bf2(v[0], v[1]), f2bf2(v[2], v[3]),
                                       f2bf2(v[4], v[5]), f2bf2(v[6], v[7]));
    }
  }
}

extern "C" void kernel_launch(void* const* d_in, const int* in_sizes, int n_in,
                              void* d_out, int out_size, void* d_ws, size_t ws_size,
                              hipStream_t stream) {
  const void* x   = d_in[0];
  const int*  ei  = (const int*)d_in[1];
  const void* W1  = d_in[2];
  const void* as1 = d_in[3];
  const void* ad1 = d_in[4];
  const void* b1  = d_in[5];
  const void* W2  = d_in[6];
  const void* as2 = d_in[7];
  const void* ad2 = d_in[8];
  const void* b2  = d_in[9];

  const int n  = in_sizes[0] / 16;        // 100000
  const int E  = in_sizes[1] / 2;         // 3200000
  const int Et = E + n;                   // + self-loops
  const int NB = (n + BSZ - 1) >> BSH;    // 782 buckets

  // ---- workspace layout ----
  char* base = (char*)d_ws;
  int* flag   = (int*)base;               // 64 B
  int* gcnt   = (int*)(base + 64);        // NB+1
  int* gbase_ = gcnt + (NB + 1);          // NB+1
  int* gcur   = gbase_ + (NB + 1);        // NB
  int* rowptr = gcur + NB;                // n+1
  int* csr    = rowptr + (n + 1);         // Et (persists through both gathers)
  size_t off1 = 64 + sizeof(int) * ((size_t)(NB + 1) * 2 + NB + (size_t)(n + 1) + (size_t)Et);
  off1 = (off1 + 255) & ~(size_t)255;
  // Union region: packed (Et ints, dead after localsort) / layer-1 bf16 tables
  // (44n bytes, written by gat_proj which runs after localsort).
  int*      packed = (int*)(base + off1);
  unsigned* hb1 = (unsigned*)(base + off1);        // 32n B: n x 16 bf16 (one 32B row)
  float*    ald1 = (float*)(base + off1 + (size_t)32 * n);   // 8n B: n x f32x2
  unsigned* ab1 = (unsigned*)(base + off1 + (size_t)40 * n); // 4n B: n x 2 bf16
  size_t usz = sizeof(int) * (size_t)Et;
  size_t fsz = (size_t)44 * n;
  size_t off2 = off1 + (usz > fsz ? usz : fsz);
  off2 = (off2 + 255) & ~(size_t)255;
  unsigned* hb2 = (unsigned*)(base + off2);        // 16n B: n x 8 bf16 (one 16B row)
  float*    ald2 = (float*)(base + off2 + (size_t)16 * n);   // 8n B
  unsigned* ab2 = (unsigned*)(base + off2 + (size_t)24 * n); // 4n B

  const int nblk   = (n + TB - 1) / TB;
  const int EB     = (Et + CHUNK - 1) / CHUNK;
  const int gblk16 = (16 * n + TB - 1) / TB;      // 16 threads per node

  detect_dtype<<<1, 64, 0, stream>>>((const unsigned short*)x, flag);

  // ---- bucket counting sort -> dst-sorted CSR (once; shared by both layers) ----
  hipMemsetAsync(gcnt, 0, (size_t)(NB + 1) * sizeof(int), stream);
  k_bcount<<<EB, TBB, 0, stream>>>(ei, E, Et, NB, gcnt);
  k_bscan<<<1, 1024, 0, stream>>>(gcnt, gbase_, gcur, NB, Et);
  k_bscatter<<<EB, TBB, 0, stream>>>(ei, E, Et, NB, gcur, packed);
  k_localsort<<<NB, 512, 0, stream>>>(gbase_, packed, rowptr, csr, n, Et);

  // ---- Layer 1 proj (after localsort: hb1 overlaps packed) ----
  gat_proj<<<nblk, TB, 0, stream>>>(x, W1, as1, ad1, hb1, ab1, ald1, n, flag);

  // ---- Layer 1 gather + finalize + fused proj2 -> layer-2 tables ----
  gat_gather1<<<gblk16, TB, 0, stream>>>(rowptr, csr, hb1, ab1, ald1, b1,
                                         W2, as2, ad2, hb2, ab2, ald2, n, flag);

  // ---- Layer 2 gather + finalize -> d_out ----
  gat_gather2<<<gblk16, TB, 0, stream>>>(rowptr, csr, hb2, ab2, ald2, b2,
                                         d_out, n, flag);
}

// Round 10
// 165.377 us; speedup vs baseline: 4.2981x; 1.0079x over previous
//
#include <hip/hip_runtime.h>
#include <hip/hip_bf16.h>

#define TB 256
#define TBB 1024         // block size for edge count/scatter (occupancy!)
#define BSH 7            // 128 nodes per bucket
#define BSZ 128
#define CHUNK 16384      // edges per block in bucket count/scatter

// Load element i of p as float, where p is either f32 (isf32=1) or bf16 bits (isf32=0).
__device__ __forceinline__ float ldany(const void* __restrict__ p, size_t i, int isf32) {
  if (isf32) return ((const float*)p)[i];
  unsigned int u = ((const unsigned short*)p)[i];
  return __uint_as_float(u << 16);
}

// Pack two f32 into two bf16 (round-to-nearest-even): [lo | hi<<16].
__device__ __forceinline__ unsigned f2bf2(float lo, float hi) {
  unsigned ul = __float_as_uint(lo), uh = __float_as_uint(hi);
  ul += 0x7FFFu + ((ul >> 16) & 1u);
  uh += 0x7FFFu + ((uh >> 16) & 1u);
  return (ul >> 16) | (uh & 0xFFFF0000u);
}
__device__ __forceinline__ float bf_lo(unsigned u) { return __uint_as_float(u << 16); }
__device__ __forceinline__ float bf_hi(unsigned u) { return __uint_as_float(u & 0xFFFF0000u); }

// Detect input float dtype: bf16 N(0,1) exponent field <= ~130; f32 misread as bf16
// gives uniform-random exponent fields, max >> 160 over 256 samples.
__global__ void detect_dtype(const unsigned short* __restrict__ xb, int* __restrict__ flag) {
  int mx = 0;
  for (int i = threadIdx.x; i < 256; i += 64) { int e = (xb[i] >> 7) & 0xFF; mx = max(mx, e); }
  #pragma unroll
  for (int off = 32; off > 0; off >>= 1) mx = max(mx, __shfl_xor(mx, off));
  if (threadIdx.x == 0) *flag = (mx > 160) ? 1 : 0;   // 1 => inputs are float32
}

// ---------------- bucket counting sort (by dst >> BSH) ----------------
__global__ __launch_bounds__(TBB) void k_bcount(const int* __restrict__ ei, int E, int Et,
                                                int NB, int* __restrict__ gcnt) {
  __shared__ int lcnt[1024];
  for (int i = threadIdx.x; i < NB; i += TBB) lcnt[i] = 0;
  __syncthreads();
  long b0 = (long)blockIdx.x * CHUNK;
  int cnt = (int)(((long)Et - b0 < (long)CHUNK) ? ((long)Et - b0) : (long)CHUNK);
  for (int i = threadIdx.x * 4; i < cnt; i += TBB * 4) {
    long e = b0 + i;
    int rem = cnt - i;
    if (rem >= 4 && e + 3 < (long)E) {
      int4 d4 = *(const int4*)(ei + E + e);      // aligned: E%4==0, e%4==0
      atomicAdd(&lcnt[d4.x >> BSH], 1);
      atomicAdd(&lcnt[d4.y >> BSH], 1);
      atomicAdd(&lcnt[d4.z >> BSH], 1);
      atomicAdd(&lcnt[d4.w >> BSH], 1);
    } else {
      int m = rem < 4 ? rem : 4;
      for (int j = 0; j < m; ++j) {
        long ee = e + j;
        int d = (ee < E) ? ei[E + ee] : (int)(ee - E);
        atomicAdd(&lcnt[d >> BSH], 1);
      }
    }
  }
  __syncthreads();
  for (int i = threadIdx.x; i < NB; i += TBB) {
    int c = lcnt[i];
    if (c) atomicAdd(&gcnt[i], c);
  }
}

// Exclusive scan over NB (<=1024) bucket counts; init cursor; set gbase[NB]=Et.
__global__ void k_bscan(const int* __restrict__ gcnt, int* __restrict__ gbase,
                        int* __restrict__ gcur, int NB, int Et) {
  __shared__ int sh[1024];
  int tid = threadIdx.x;
  int v = (tid < NB) ? gcnt[tid] : 0;
  sh[tid] = v;
  __syncthreads();
  for (int off = 1; off < 1024; off <<= 1) {
    int t = (tid >= off) ? sh[tid - off] : 0;
    __syncthreads();
    sh[tid] += t;
    __syncthreads();
  }
  if (tid < NB) { int b = sh[tid] - v; gbase[tid] = b; gcur[tid] = b; }
  if (tid == 0) gbase[NB] = Et;
}

// Scatter packed edges ((dst&127)<<17 | src) into bucket-ordered array.
__global__ __launch_bounds__(TBB) void k_bscatter(const int* __restrict__ ei, int E, int Et,
                                                  int NB, int* __restrict__ gcur,
                                                  int* __restrict__ packed) {
  __shared__ int lcnt[1024];
  __shared__ int lbase[1024];
  for (int i = threadIdx.x; i < NB; i += TBB) lcnt[i] = 0;
  __syncthreads();
  long b0 = (long)blockIdx.x * CHUNK;
  int cnt = (int)(((long)Et - b0 < (long)CHUNK) ? ((long)Et - b0) : (long)CHUNK);
  for (int i = threadIdx.x * 4; i < cnt; i += TBB * 4) {
    long e = b0 + i;
    int rem = cnt - i;
    if (rem >= 4 && e + 3 < (long)E) {
      int4 d4 = *(const int4*)(ei + E + e);
      atomicAdd(&lcnt[d4.x >> BSH], 1);
      atomicAdd(&lcnt[d4.y >> BSH], 1);
      atomicAdd(&lcnt[d4.z >> BSH], 1);
      atomicAdd(&lcnt[d4.w >> BSH], 1);
    } else {
      int m = rem < 4 ? rem : 4;
      for (int j = 0; j < m; ++j) {
        long ee = e + j;
        int d = (ee < E) ? ei[E + ee] : (int)(ee - E);
        atomicAdd(&lcnt[d >> BSH], 1);
      }
    }
  }
  __syncthreads();
  for (int i = threadIdx.x; i < NB; i += TBB) {
    int c = lcnt[i];
    lbase[i] = c ? atomicAdd(&gcur[i], c) : 0;
  }
  __syncthreads();
  for (int i = threadIdx.x * 4; i < cnt; i += TBB * 4) {
    long e = b0 + i;
    int rem = cnt - i;
    if (rem >= 4 && e + 3 < (long)E) {
      int4 s4 = *(const int4*)(ei + e);
      int4 d4 = *(const int4*)(ei + E + e);
      int bk, pos;
      bk = d4.x >> BSH; pos = atomicAdd(&lbase[bk], 1); packed[pos] = ((d4.x & (BSZ-1)) << 17) | s4.x;
      bk = d4.y >> BSH; pos = atomicAdd(&lbase[bk], 1); packed[pos] = ((d4.y & (BSZ-1)) << 17) | s4.y;
      bk = d4.z >> BSH; pos = atomicAdd(&lbase[bk], 1); packed[pos] = ((d4.z & (BSZ-1)) << 17) | s4.z;
      bk = d4.w >> BSH; pos = atomicAdd(&lbase[bk], 1); packed[pos] = ((d4.w & (BSZ-1)) << 17) | s4.w;
    } else {
      int m = rem < 4 ? rem : 4;
      for (int j = 0; j < m; ++j) {
        long ee = e + j;
        int s, d;
        if (ee < E) { s = ei[ee]; d = ei[E + ee]; }
        else        { s = (int)(ee - E); d = s; }
        int bk = d >> BSH;
        int pos = atomicAdd(&lbase[bk], 1);
        packed[pos] = ((d & (BSZ - 1)) << 17) | s;
      }
    }
  }
}

// Local counting sort within each bucket -> full dst-sorted CSR + rowptr.
__global__ __launch_bounds__(512) void k_localsort(const int* __restrict__ gbase,
                                                   const int* __restrict__ packed,
                                                   int* __restrict__ rowptr,
                                                   int* __restrict__ csr,
                                                   int n, int Et) {
  __shared__ int lcnt[BSZ], lbase[BSZ], sh[BSZ];
  const int b = blockIdx.x;
  const int node0 = b << BSH;
  const int tid = threadIdx.x;
  if (tid < BSZ) lcnt[tid] = 0;
  __syncthreads();
  const int beg = gbase[b], end = gbase[b + 1];
  for (int k = beg + tid; k < end; k += 512)
    atomicAdd(&lcnt[packed[k] >> 17], 1);
  __syncthreads();
  int v = (tid < BSZ) ? lcnt[tid] : 0;
  if (tid < BSZ) sh[tid] = v;
  __syncthreads();
  for (int off = 1; off < BSZ; off <<= 1) {
    int t = (tid < BSZ && tid >= off) ? sh[tid - off] : 0;
    __syncthreads();
    if (tid < BSZ) sh[tid] += t;
    __syncthreads();
  }
  if (tid < BSZ) lbase[tid] = sh[tid] - v;
  __syncthreads();
  const int nn = min(BSZ, n - node0);
  if (tid < nn) rowptr[node0 + tid] = beg + lbase[tid];
  if (b == 0 && tid == 0) rowptr[n] = Et;
  for (int k = beg + tid; k < end; k += 512) {
    int p = packed[k];
    int dl = p >> 17;
    int pos = beg + atomicAdd(&lbase[dl], 1);
    csr[pos] = p & 0x1FFFF;
  }
}

// ---------------- Projection (layer 1): bf16 tables hb1[n][16], ab1[n]; f32 ald --
__global__ void gat_proj(const void* __restrict__ xin,
                         const void* __restrict__ Wg,
                         const void* __restrict__ asg,
                         const void* __restrict__ adg,
                         unsigned* __restrict__ hb,     // n x 8 uints (16 bf16)
                         unsigned* __restrict__ ab,     // n x (2 bf16 als)
                         float* __restrict__ ald,       // n x 2 f32
                         int n, const int* __restrict__ flag) {
  const int isf = *flag;
  __shared__ float Ws[16 * 16];
  __shared__ float as_s[16], ad_s[16];
  for (int i = threadIdx.x; i < 256; i += blockDim.x) Ws[i] = ldany(Wg, i, isf);
  if (threadIdx.x < 16) {
    as_s[threadIdx.x] = ldany(asg, threadIdx.x, isf);
    ad_s[threadIdx.x] = ldany(adg, threadIdx.x, isf);
  }
  __syncthreads();
  int nid = blockIdx.x * blockDim.x + threadIdx.x;
  if (nid >= n) return;

  float xr[16];
  #pragma unroll
  for (int i = 0; i < 16; ++i) xr[i] = ldany(xin, (size_t)nid * 16 + i, isf);

  float hv[16];
  #pragma unroll
  for (int j = 0; j < 16; ++j) hv[j] = 0.f;
  #pragma unroll
  for (int k = 0; k < 16; ++k) {
    #pragma unroll
    for (int j = 0; j < 16; ++j) hv[j] += xr[k] * Ws[k * 16 + j];
  }

  unsigned* row = hb + (size_t)nid * 8;
  ((uint4*)row)[0] = make_uint4(f2bf2(hv[0], hv[1]),  f2bf2(hv[2], hv[3]),
                                f2bf2(hv[4], hv[5]),  f2bf2(hv[6], hv[7]));
  ((uint4*)row)[1] = make_uint4(f2bf2(hv[8], hv[9]),  f2bf2(hv[10], hv[11]),
                                f2bf2(hv[12], hv[13]), f2bf2(hv[14], hv[15]));

  float s0 = 0.f, d0 = 0.f, s1 = 0.f, d1 = 0.f;
  #pragma unroll
  for (int c = 0; c < 8; ++c) {
    s0 += hv[c] * as_s[c];         d0 += hv[c] * ad_s[c];
    s1 += hv[8 + c] * as_s[8 + c]; d1 += hv[8 + c] * ad_s[8 + c];
  }
  ab[nid] = f2bf2(s0, s1);
  ((float2*)ald)[nid] = make_float2(d0, d1);
}

// ---------------- Layer-1 gather: 16 lanes/node, 2 lanes/edge, 2-deep pipeline ---
// Fused: softmax-normalize + bias + ELU + proj2(W2,att2) -> layer-2 bf16 tables.
__global__ __launch_bounds__(TB) void
gat_gather1(const int* __restrict__ rowptr, const int* __restrict__ csr,
            const unsigned* __restrict__ hb, const unsigned* __restrict__ ab,
            const float* __restrict__ ald,
            const void* __restrict__ bias,
            const void* __restrict__ W2g, const void* __restrict__ as2g,
            const void* __restrict__ ad2g,
            unsigned* __restrict__ hb2, unsigned* __restrict__ ab2,
            float* __restrict__ ald2,
            int n, const int* __restrict__ flag) {
  const int isf = *flag;
  __shared__ float sb[16];
  __shared__ float sv[16 * 17];
  __shared__ float W2s[128];
  __shared__ float as2s[8], ad2s[8];
  if (threadIdx.x < 16) sb[threadIdx.x] = ldany(bias, threadIdx.x, isf);
  for (int i = threadIdx.x; i < 128; i += TB) W2s[i] = ldany(W2g, i, isf);
  if (threadIdx.x < 8) {
    as2s[threadIdx.x] = ldany(as2g, threadIdx.x, isf);
    ad2s[threadIdx.x] = ldany(ad2g, threadIdx.x, isf);
  }
  __syncthreads();

  const int t = blockIdx.x * TB + threadIdx.x;
  const int sub = t & 15, nid = t >> 4;
  const int slot = sub >> 1, hq = sub & 1;      // 8 edge slots x 2 head-lanes
  const bool act = nid < n;
  int beg = 0, end = 0;
  float aldv = 0.f;
  if (act) {
    beg = rowptr[nid];
    end = rowptr[nid + 1];
    aldv = ald[(size_t)nid * 2 + hq];
  }

  float acc[8];
  #pragma unroll
  for (int c = 0; c < 8; ++c) acc[c] = 0.f;
  float z = 0.f;

  // ---- 2-deep software pipeline: row/ab loads 1 iter ahead, csr 2 ahead ----
  int k  = beg + slot;
  int kn = k + 8;
  int s_cur = (k  < end) ? csr[k]  : 0;
  int s_nxt = (kn < end) ? csr[kn] : 0;
  uint4    u_cur = *(const uint4*)(hb + (size_t)s_cur * 8 + hq * 4);
  unsigned a_cur = ab[s_cur];
  while (k < end) {
    uint4    u_n = *(const uint4*)(hb + (size_t)s_nxt * 8 + hq * 4);  // next row
    unsigned a_n = ab[s_nxt];
    int kf = kn + 8;
    int s_f = (kf < end) ? csr[kf] : 0;          // csr two ahead
    // compute current edge
    float alsv = hq ? bf_hi(a_cur) : bf_lo(a_cur);
    float lg = alsv + aldv;
    lg = lg > 0.f ? lg : 0.2f * lg;              // leaky_relu slope 0.2
    float w = __expf(lg);
    z += w;
    acc[0] += w * bf_lo(u_cur.x); acc[1] += w * bf_hi(u_cur.x);
    acc[2] += w * bf_lo(u_cur.y); acc[3] += w * bf_hi(u_cur.y);
    acc[4] += w * bf_lo(u_cur.z); acc[5] += w * bf_hi(u_cur.z);
    acc[6] += w * bf_lo(u_cur.w); acc[7] += w * bf_hi(u_cur.w);
    // shift pipeline
    k = kn; kn = kf; s_cur = s_nxt; s_nxt = s_f; u_cur = u_n; a_cur = a_n;
  }

  #pragma unroll
  for (int off = 2; off < 16; off <<= 1) {      // combine slots, keep head bit
    z += __shfl_xor(z, off);
    #pragma unroll
    for (int c = 0; c < 8; ++c) acc[c] += __shfl_xor(acc[c], off);
  }
  float inv = 1.f / (z + 1e-16f);

  if (act && slot == 0) {                       // lanes sub=0(head0),1(head1)
    int ns = threadIdx.x >> 4;
    #pragma unroll
    for (int c = 0; c < 8; ++c) {
      float v = acc[c] * inv + sb[hq * 8 + c];
      v = v > 0.f ? v : expm1f(v);              // ELU
      sv[ns * 17 + hq * 8 + c] = v;
    }
  }
  __syncthreads();
  if (threadIdx.x < 16) {
    int nid2 = blockIdx.x * 16 + threadIdx.x;
    if (nid2 < n) {
      float h2[8];
      #pragma unroll
      for (int j = 0; j < 8; ++j) h2[j] = 0.f;
      #pragma unroll
      for (int kk = 0; kk < 16; ++kk) {
        float v = sv[threadIdx.x * 17 + kk];
        #pragma unroll
        for (int j = 0; j < 8; ++j) h2[j] += v * W2s[kk * 8 + j];
      }
      ((uint4*)(hb2 + (size_t)nid2 * 4))[0] =
          make_uint4(f2bf2(h2[0], h2[1]), f2bf2(h2[2], h2[3]),
                     f2bf2(h2[4], h2[5]), f2bf2(h2[6], h2[7]));
      float s20 = 0.f, d20 = 0.f, s21 = 0.f, d21 = 0.f;
      #pragma unroll
      for (int c = 0; c < 4; ++c) {
        s20 += h2[c] * as2s[c];         d20 += h2[c] * ad2s[c];
        s21 += h2[4 + c] * as2s[4 + c]; d21 += h2[4 + c] * ad2s[4 + c];
      }
      ab2[nid2] = f2bf2(s20, s21);
      ((float2*)ald2)[nid2] = make_float2(d20, d21);
    }
  }
}

// ---------------- Layer-2 gather: 16 lanes/node, 2 lanes/edge (8B), pipelined ----
__global__ __launch_bounds__(TB) void
gat_gather2(const int* __restrict__ rowptr, const int* __restrict__ csr,
            const unsigned* __restrict__ hb2, const unsigned* __restrict__ ab2,
            const float* __restrict__ ald2,
            const void* __restrict__ bias,
            void* __restrict__ outp, int n, const int* __restrict__ flag) {
  const int isf = *flag;
  __shared__ float sb[8];
  if (threadIdx.x < 8) sb[threadIdx.x] = ldany(bias, threadIdx.x, isf);
  __syncthreads();

  const int t = blockIdx.x * TB + threadIdx.x;
  const int sub = t & 15, nid = t >> 4;
  const int slot = sub >> 1, hq = sub & 1;      // 8 edge slots x 2 head-lanes
  const bool act = nid < n;
  int beg = 0, end = 0;
  float aldv = 0.f;
  if (act) {
    beg = rowptr[nid];
    end = rowptr[nid + 1];
    aldv = ald2[(size_t)nid * 2 + hq];
  }

  float a0 = 0.f, a1 = 0.f, a2 = 0.f, a3 = 0.f, z = 0.f;

  int k  = beg + slot;
  int kn = k + 8;
  int s_cur = (k  < end) ? csr[k]  : 0;
  int s_nxt = (kn < end) ? csr[kn] : 0;
  uint2    u_cur = *(const uint2*)(hb2 + (size_t)s_cur * 4 + hq * 2);
  unsigned ab_cur = ab2[s_cur];
  while (k < end) {
    uint2    u_n = *(const uint2*)(hb2 + (size_t)s_nxt * 4 + hq * 2);
    unsigned ab_n = ab2[s_nxt];
    int kf = kn + 8;
    int s_f = (kf < end) ? csr[kf] : 0;
    float alsv = hq ? bf_hi(ab_cur) : bf_lo(ab_cur);
    float lg = alsv + aldv;
    lg = lg > 0.f ? lg : 0.2f * lg;
    float w = __expf(lg);
    z += w;
    a0 += w * bf_lo(u_cur.x); a1 += w * bf_hi(u_cur.x);
    a2 += w * bf_lo(u_cur.y); a3 += w * bf_hi(u_cur.y);
    k = kn; kn = kf; s_cur = s_nxt; s_nxt = s_f; u_cur = u_n; ab_cur = ab_n;
  }

  #pragma unroll
  for (int off = 2; off < 16; off <<= 1) {      // combine slots, keep head bit
    z  += __shfl_xor(z, off);
    a0 += __shfl_xor(a0, off); a1 += __shfl_xor(a1, off);
    a2 += __shfl_xor(a2, off); a3 += __shfl_xor(a3, off);
  }

  if (act && slot == 0) {                       // lanes sub=0(head0),1(head1)
    float inv = 1.f / (z + 1e-16f);
    float v0 = a0 * inv + sb[hq * 4 + 0];
    float v1 = a1 * inv + sb[hq * 4 + 1];
    float v2 = a2 * inv + sb[hq * 4 + 2];
    float v3 = a3 * inv + sb[hq * 4 + 3];
    if (isf) {
      ((float4*)outp)[(size_t)nid * 2 + hq] = make_float4(v0, v1, v2, v3);
    } else {
      ((uint2*)outp)[(size_t)nid * 2 + hq] = make_uint2(f2bf2(v0, v1), f2bf2(v2, v3));
    }
  }
}

extern "C" void kernel_launch(void* const* d_in, const int* in_sizes, int n_in,
                              void* d_out, int out_size, void* d_ws, size_t ws_size,
                              hipStream_t stream) {
  const void* x   = d_in[0];
  const int*  ei  = (const int*)d_in[1];
  const void* W1  = d_in[2];
  const void* as1 = d_in[3];
  const void* ad1 = d_in[4];
  const void* b1  = d_in[5];
  const void* W2  = d_in[6];
  const void* as2 = d_in[7];
  const void* ad2 = d_in[8];
  const void* b2  = d_in[9];

  const int n  = in_sizes[0] / 16;        // 100000
  const int E  = in_sizes[1] / 2;         // 3200000
  const int Et = E + n;                   // + self-loops
  const int NB = (n + BSZ - 1) >> BSH;    // 782 buckets

  // ---- workspace layout ----
  char* base = (char*)d_ws;
  int* flag   = (int*)base;               // 64 B
  int* gcnt   = (int*)(base + 64);        // NB+1
  int* gbase_ = gcnt + (NB + 1);          // NB+1
  int* gcur   = gbase_ + (NB + 1);        // NB
  int* rowptr = gcur + NB;                // n+1
  int* csr    = rowptr + (n + 1);         // Et (persists through both gathers)
  size_t off1 = 64 + sizeof(int) * ((size_t)(NB + 1) * 2 + NB + (size_t)(n + 1) + (size_t)Et);
  off1 = (off1 + 255) & ~(size_t)255;
  // Union region: packed (Et ints, dead after localsort) / layer-1 bf16 tables
  // (44n bytes, written by gat_proj which runs after localsort).
  int*      packed = (int*)(base + off1);
  unsigned* hb1 = (unsigned*)(base + off1);        // 32n B: n x 16 bf16 (one 32B row)
  float*    ald1 = (float*)(base + off1 + (size_t)32 * n);   // 8n B: n x f32x2
  unsigned* ab1 = (unsigned*)(base + off1 + (size_t)40 * n); // 4n B: n x 2 bf16
  size_t usz = sizeof(int) * (size_t)Et;
  size_t fsz = (size_t)44 * n;
  size_t off2 = off1 + (usz > fsz ? usz : fsz);
  off2 = (off2 + 255) & ~(size_t)255;
  unsigned* hb2 = (unsigned*)(base + off2);        // 16n B: n x 8 bf16 (one 16B row)
  float*    ald2 = (float*)(base + off2 + (size_t)16 * n);   // 8n B
  unsigned* ab2 = (unsigned*)(base + off2 + (size_t)24 * n); // 4n B

  const int nblk   = (n + TB - 1) / TB;
  const int EB     = (Et + CHUNK - 1) / CHUNK;
  const int gblk16 = (16 * n + TB - 1) / TB;      // 16 threads per node

  detect_dtype<<<1, 64, 0, stream>>>((const unsigned short*)x, flag);

  // ---- bucket counting sort -> dst-sorted CSR (once; shared by both layers) ----
  hipMemsetAsync(gcnt, 0, (size_t)(NB + 1) * sizeof(int), stream);
  k_bcount<<<EB, TBB, 0, stream>>>(ei, E, Et, NB, gcnt);
  k_bscan<<<1, 1024, 0, stream>>>(gcnt, gbase_, gcur, NB, Et);
  k_bscatter<<<EB, TBB, 0, stream>>>(ei, E, Et, NB, gcur, packed);
  k_localsort<<<NB, 512, 0, stream>>>(gbase_, packed, rowptr, csr, n, Et);

  // ---- Layer 1 proj (after localsort: hb1 overlaps packed) ----
  gat_proj<<<nblk, TB, 0, stream>>>(x, W1, as1, ad1, hb1, ab1, ald1, n, flag);

  // ---- Layer 1 gather + finalize + fused proj2 -> layer-2 tables ----
  gat_gather1<<<gblk16, TB, 0, stream>>>(rowptr, csr, hb1, ab1, ald1, b1,
                                         W2, as2, ad2, hb2, ab2, ald2, n, flag);

  // ---- Layer 2 gather + finalize -> d_out ----
  gat_gather2<<<gblk16, TB, 0, stream>>>(rowptr, csr, hb2, ab2, ald2, b2,
                                         d_out, n, flag);
}

// Round 11
// 162.945 us; speedup vs baseline: 4.3622x; 1.0149x over previous
//
#include <hip/hip_runtime.h>
#include <hip/hip_bf16.h>

#define TB 256
#define TBB 512          // block size for edge count/scatter
#define BSH 7            // 128 nodes per bucket
#define BSZ 128
#define CHUNK 4096       // edges per block in bucket count/scatter
#define EBP 1024         // padded blocks-per-bucket stride (EB <= 1024)

// Load element i of p as float, where p is either f32 (isf32=1) or bf16 bits (isf32=0).
__device__ __forceinline__ float ldany(const void* __restrict__ p, size_t i, int isf32) {
  if (isf32) return ((const float*)p)[i];
  unsigned int u = ((const unsigned short*)p)[i];
  return __uint_as_float(u << 16);
}

// Pack two f32 into two bf16 (round-to-nearest-even): [lo | hi<<16].
__device__ __forceinline__ unsigned f2bf2(float lo, float hi) {
  unsigned ul = __float_as_uint(lo), uh = __float_as_uint(hi);
  ul += 0x7FFFu + ((ul >> 16) & 1u);
  uh += 0x7FFFu + ((uh >> 16) & 1u);
  return (ul >> 16) | (uh & 0xFFFF0000u);
}
__device__ __forceinline__ float bf_lo(unsigned u) { return __uint_as_float(u << 16); }
__device__ __forceinline__ float bf_hi(unsigned u) { return __uint_as_float(u & 0xFFFF0000u); }

// Detect input float dtype: bf16 N(0,1) exponent field <= ~130; f32 misread as bf16
// gives uniform-random exponent fields, max >> 160 over 256 samples.
__global__ void detect_dtype(const unsigned short* __restrict__ xb, int* __restrict__ flag) {
  int mx = 0;
  for (int i = threadIdx.x; i < 256; i += 64) { int e = (xb[i] >> 7) & 0xFF; mx = max(mx, e); }
  #pragma unroll
  for (int off = 32; off > 0; off >>= 1) mx = max(mx, __shfl_xor(mx, off));
  if (threadIdx.x == 0) *flag = (mx > 160) ? 1 : 0;   // 1 => inputs are float32
}

// ---------------- pass 1: per-block bucket histogram -> bcnt[bk*EBP + blk] ------
__global__ __launch_bounds__(TBB) void k_bcount(const int* __restrict__ ei, int E, int Et,
                                                int NB, int* __restrict__ bcnt) {
  __shared__ int lcnt[1024];
  for (int i = threadIdx.x; i < NB; i += TBB) lcnt[i] = 0;
  __syncthreads();
  long b0 = (long)blockIdx.x * CHUNK;
  int cnt = (int)(((long)Et - b0 < (long)CHUNK) ? ((long)Et - b0) : (long)CHUNK);
  for (int i = threadIdx.x * 4; i < cnt; i += TBB * 4) {
    long e = b0 + i;
    int rem = cnt - i;
    if (rem >= 4 && e + 3 < (long)E) {
      int4 d4 = *(const int4*)(ei + E + e);      // aligned: E%4==0, e%4==0
      atomicAdd(&lcnt[d4.x >> BSH], 1);
      atomicAdd(&lcnt[d4.y >> BSH], 1);
      atomicAdd(&lcnt[d4.z >> BSH], 1);
      atomicAdd(&lcnt[d4.w >> BSH], 1);
    } else {
      int m = rem < 4 ? rem : 4;
      for (int j = 0; j < m; ++j) {
        long ee = e + j;
        int d = (ee < E) ? ei[E + ee] : (int)(ee - E);
        atomicAdd(&lcnt[d >> BSH], 1);
      }
    }
  }
  __syncthreads();
  for (int i = threadIdx.x; i < NB; i += TBB)
    bcnt[(size_t)i * EBP + blockIdx.x] = lcnt[i];
}

// ---------------- pass 2: per-bucket exclusive scan over blocks -----------------
// block = bucket. In-place: bcnt[bk][blk] -> exclusive prefix; totals -> gcnt[bk].
__global__ __launch_bounds__(1024) void k_blockpfx(int* __restrict__ bcnt,
                                                   int* __restrict__ gcnt,
                                                   int EB, int NB) {
  __shared__ int sh[1024];
  const int bk = blockIdx.x;
  const int tid = threadIdx.x;
  int v = (tid < EB) ? bcnt[(size_t)bk * EBP + tid] : 0;
  sh[tid] = v;
  __syncthreads();
  for (int off = 1; off < 1024; off <<= 1) {
    int t = (tid >= off) ? sh[tid - off] : 0;
    __syncthreads();
    sh[tid] += t;
    __syncthreads();
  }
  if (tid < EB) bcnt[(size_t)bk * EBP + tid] = sh[tid] - v;   // exclusive
  if (tid == 0) gcnt[bk] = sh[1023];                          // bucket total
}

// Exclusive scan over NB (<=1024) bucket totals; set gbase[NB]=Et.
__global__ void k_bscan(const int* __restrict__ gcnt, int* __restrict__ gbase,
                        int NB, int Et) {
  __shared__ int sh[1024];
  int tid = threadIdx.x;
  int v = (tid < NB) ? gcnt[tid] : 0;
  sh[tid] = v;
  __syncthreads();
  for (int off = 1; off < 1024; off <<= 1) {
    int t = (tid >= off) ? sh[tid - off] : 0;
    __syncthreads();
    sh[tid] += t;
    __syncthreads();
  }
  if (tid < NB) gbase[tid] = sh[tid] - v;
  if (tid == 0) gbase[NB] = Et;
}

// ---------------- pass 3: single-pass scatter using precomputed bases -----------
// lcur[bk] = gbase[bk] + bcnt[bk][blk]; per edge: one LDS atomic + one write.
__global__ __launch_bounds__(TBB) void k_bscatter(const int* __restrict__ ei, int E, int Et,
                                                  int NB, const int* __restrict__ gbase,
                                                  const int* __restrict__ bcnt,
                                                  int* __restrict__ packed) {
  __shared__ int lcur[1024];
  const int b = blockIdx.x;
  for (int i = threadIdx.x; i < NB; i += TBB)
    lcur[i] = gbase[i] + bcnt[(size_t)i * EBP + b];
  __syncthreads();
  long b0 = (long)b * CHUNK;
  int cnt = (int)(((long)Et - b0 < (long)CHUNK) ? ((long)Et - b0) : (long)CHUNK);
  for (int i = threadIdx.x * 4; i < cnt; i += TBB * 4) {
    long e = b0 + i;
    int rem = cnt - i;
    if (rem >= 4 && e + 3 < (long)E) {
      int4 s4 = *(const int4*)(ei + e);
      int4 d4 = *(const int4*)(ei + E + e);
      int bk, pos;
      bk = d4.x >> BSH; pos = atomicAdd(&lcur[bk], 1); packed[pos] = ((d4.x & (BSZ-1)) << 17) | s4.x;
      bk = d4.y >> BSH; pos = atomicAdd(&lcur[bk], 1); packed[pos] = ((d4.y & (BSZ-1)) << 17) | s4.y;
      bk = d4.z >> BSH; pos = atomicAdd(&lcur[bk], 1); packed[pos] = ((d4.z & (BSZ-1)) << 17) | s4.z;
      bk = d4.w >> BSH; pos = atomicAdd(&lcur[bk], 1); packed[pos] = ((d4.w & (BSZ-1)) << 17) | s4.w;
    } else {
      int m = rem < 4 ? rem : 4;
      for (int j = 0; j < m; ++j) {
        long ee = e + j;
        int s, d;
        if (ee < E) { s = ei[ee]; d = ei[E + ee]; }
        else        { s = (int)(ee - E); d = s; }
        int bk = d >> BSH;
        int pos = atomicAdd(&lcur[bk], 1);
        packed[pos] = ((d & (BSZ - 1)) << 17) | s;
      }
    }
  }
}

// Local counting sort within each bucket -> full dst-sorted CSR + rowptr.
__global__ __launch_bounds__(512) void k_localsort(const int* __restrict__ gbase,
                                                   const int* __restrict__ packed,
                                                   int* __restrict__ rowptr,
                                                   int* __restrict__ csr,
                                                   int n, int Et) {
  __shared__ int lcnt[BSZ], lbase[BSZ], sh[BSZ];
  const int b = blockIdx.x;
  const int node0 = b << BSH;
  const int tid = threadIdx.x;
  if (tid < BSZ) lcnt[tid] = 0;
  __syncthreads();
  const int beg = gbase[b], end = gbase[b + 1];
  for (int k = beg + tid; k < end; k += 512)
    atomicAdd(&lcnt[packed[k] >> 17], 1);
  __syncthreads();
  int v = (tid < BSZ) ? lcnt[tid] : 0;
  if (tid < BSZ) sh[tid] = v;
  __syncthreads();
  for (int off = 1; off < BSZ; off <<= 1) {
    int t = (tid < BSZ && tid >= off) ? sh[tid - off] : 0;
    __syncthreads();
    if (tid < BSZ) sh[tid] += t;
    __syncthreads();
  }
  if (tid < BSZ) lbase[tid] = sh[tid] - v;
  __syncthreads();
  const int nn = min(BSZ, n - node0);
  if (tid < nn) rowptr[node0 + tid] = beg + lbase[tid];
  if (b == 0 && tid == 0) rowptr[n] = Et;
  for (int k = beg + tid; k < end; k += 512) {
    int p = packed[k];
    int dl = p >> 17;
    int pos = beg + atomicAdd(&lbase[dl], 1);
    csr[pos] = p & 0x1FFFF;
  }
}

// ---------------- Projection (layer 1): bf16 tables hb1[n][16], ab1[n]; f32 ald --
__global__ void gat_proj(const void* __restrict__ xin,
                         const void* __restrict__ Wg,
                         const void* __restrict__ asg,
                         const void* __restrict__ adg,
                         unsigned* __restrict__ hb,     // n x 8 uints (16 bf16)
                         unsigned* __restrict__ ab,     // n x (2 bf16 als)
                         float* __restrict__ ald,       // n x 2 f32
                         int n, const int* __restrict__ flag) {
  const int isf = *flag;
  __shared__ float Ws[16 * 16];
  __shared__ float as_s[16], ad_s[16];
  for (int i = threadIdx.x; i < 256; i += blockDim.x) Ws[i] = ldany(Wg, i, isf);
  if (threadIdx.x < 16) {
    as_s[threadIdx.x] = ldany(asg, threadIdx.x, isf);
    ad_s[threadIdx.x] = ldany(adg, threadIdx.x, isf);
  }
  __syncthreads();
  int nid = blockIdx.x * blockDim.x + threadIdx.x;
  if (nid >= n) return;

  float xr[16];
  #pragma unroll
  for (int i = 0; i < 16; ++i) xr[i] = ldany(xin, (size_t)nid * 16 + i, isf);

  float hv[16];
  #pragma unroll
  for (int j = 0; j < 16; ++j) hv[j] = 0.f;
  #pragma unroll
  for (int k = 0; k < 16; ++k) {
    #pragma unroll
    for (int j = 0; j < 16; ++j) hv[j] += xr[k] * Ws[k * 16 + j];
  }

  unsigned* row = hb + (size_t)nid * 8;
  ((uint4*)row)[0] = make_uint4(f2bf2(hv[0], hv[1]),  f2bf2(hv[2], hv[3]),
                                f2bf2(hv[4], hv[5]),  f2bf2(hv[6], hv[7]));
  ((uint4*)row)[1] = make_uint4(f2bf2(hv[8], hv[9]),  f2bf2(hv[10], hv[11]),
                                f2bf2(hv[12], hv[13]), f2bf2(hv[14], hv[15]));

  float s0 = 0.f, d0 = 0.f, s1 = 0.f, d1 = 0.f;
  #pragma unroll
  for (int c = 0; c < 8; ++c) {
    s0 += hv[c] * as_s[c];         d0 += hv[c] * ad_s[c];
    s1 += hv[8 + c] * as_s[8 + c]; d1 += hv[8 + c] * ad_s[8 + c];
  }
  ab[nid] = f2bf2(s0, s1);
  ((float2*)ald)[nid] = make_float2(d0, d1);
}

// ---------------- Layer-1 gather: 16 lanes/node, 2 lanes/edge, 2-deep pipeline ---
// Fused: softmax-normalize + bias + ELU + proj2(W2,att2) -> layer-2 bf16 tables.
__global__ __launch_bounds__(TB) void
gat_gather1(const int* __restrict__ rowptr, const int* __restrict__ csr,
            const unsigned* __restrict__ hb, const unsigned* __restrict__ ab,
            const float* __restrict__ ald,
            const void* __restrict__ bias,
            const void* __restrict__ W2g, const void* __restrict__ as2g,
            const void* __restrict__ ad2g,
            unsigned* __restrict__ hb2, unsigned* __restrict__ ab2,
            float* __restrict__ ald2,
            int n, const int* __restrict__ flag) {
  const int isf = *flag;
  __shared__ float sb[16];
  __shared__ float sv[16 * 17];
  __shared__ float W2s[128];
  __shared__ float as2s[8], ad2s[8];
  if (threadIdx.x < 16) sb[threadIdx.x] = ldany(bias, threadIdx.x, isf);
  for (int i = threadIdx.x; i < 128; i += TB) W2s[i] = ldany(W2g, i, isf);
  if (threadIdx.x < 8) {
    as2s[threadIdx.x] = ldany(as2g, threadIdx.x, isf);
    ad2s[threadIdx.x] = ldany(ad2g, threadIdx.x, isf);
  }
  __syncthreads();

  const int t = blockIdx.x * TB + threadIdx.x;
  const int sub = t & 15, nid = t >> 4;
  const int slot = sub >> 1, hq = sub & 1;      // 8 edge slots x 2 head-lanes
  const bool act = nid < n;
  int beg = 0, end = 0;
  float aldv = 0.f;
  if (act) {
    beg = rowptr[nid];
    end = rowptr[nid + 1];
    aldv = ald[(size_t)nid * 2 + hq];
  }

  float acc[8];
  #pragma unroll
  for (int c = 0; c < 8; ++c) acc[c] = 0.f;
  float z = 0.f;

  // ---- 2-deep software pipeline: row/ab loads 1 iter ahead, csr 2 ahead ----
  int k  = beg + slot;
  int kn = k + 8;
  int s_cur = (k  < end) ? csr[k]  : 0;
  int s_nxt = (kn < end) ? csr[kn] : 0;
  uint4    u_cur = *(const uint4*)(hb + (size_t)s_cur * 8 + hq * 4);
  unsigned a_cur = ab[s_cur];
  while (k < end) {
    uint4    u_n = *(const uint4*)(hb + (size_t)s_nxt * 8 + hq * 4);  // next row
    unsigned a_n = ab[s_nxt];
    int kf = kn + 8;
    int s_f = (kf < end) ? csr[kf] : 0;          // csr two ahead
    // compute current edge
    float alsv = hq ? bf_hi(a_cur) : bf_lo(a_cur);
    float lg = alsv + aldv;
    lg = lg > 0.f ? lg : 0.2f * lg;              // leaky_relu slope 0.2
    float w = __expf(lg);
    z += w;
    acc[0] += w * bf_lo(u_cur.x); acc[1] += w * bf_hi(u_cur.x);
    acc[2] += w * bf_lo(u_cur.y); acc[3] += w * bf_hi(u_cur.y);
    acc[4] += w * bf_lo(u_cur.z); acc[5] += w * bf_hi(u_cur.z);
    acc[6] += w * bf_lo(u_cur.w); acc[7] += w * bf_hi(u_cur.w);
    // shift pipeline
    k = kn; kn = kf; s_cur = s_nxt; s_nxt = s_f; u_cur = u_n; a_cur = a_n;
  }

  #pragma unroll
  for (int off = 2; off < 16; off <<= 1) {      // combine slots, keep head bit
    z += __shfl_xor(z, off);
    #pragma unroll
    for (int c = 0; c < 8; ++c) acc[c] += __shfl_xor(acc[c], off);
  }
  float inv = 1.f / (z + 1e-16f);

  if (act && slot == 0) {                       // lanes sub=0(head0),1(head1)
    int ns = threadIdx.x >> 4;
    #pragma unroll
    for (int c = 0; c < 8; ++c) {
      float v = acc[c] * inv + sb[hq * 8 + c];
      v = v > 0.f ? v : expm1f(v);              // ELU
      sv[ns * 17 + hq * 8 + c] = v;
    }
  }
  __syncthreads();
  if (threadIdx.x < 16) {
    int nid2 = blockIdx.x * 16 + threadIdx.x;
    if (nid2 < n) {
      float h2[8];
      #pragma unroll
      for (int j = 0; j < 8; ++j) h2[j] = 0.f;
      #pragma unroll
      for (int kk = 0; kk < 16; ++kk) {
        float v = sv[threadIdx.x * 17 + kk];
        #pragma unroll
        for (int j = 0; j < 8; ++j) h2[j] += v * W2s[kk * 8 + j];
      }
      ((uint4*)(hb2 + (size_t)nid2 * 4))[0] =
          make_uint4(f2bf2(h2[0], h2[1]), f2bf2(h2[2], h2[3]),
                     f2bf2(h2[4], h2[5]), f2bf2(h2[6], h2[7]));
      float s20 = 0.f, d20 = 0.f, s21 = 0.f, d21 = 0.f;
      #pragma unroll
      for (int c = 0; c < 4; ++c) {
        s20 += h2[c] * as2s[c];         d20 += h2[c] * ad2s[c];
        s21 += h2[4 + c] * as2s[4 + c]; d21 += h2[4 + c] * ad2s[4 + c];
      }
      ab2[nid2] = f2bf2(s20, s21);
      ((float2*)ald2)[nid2] = make_float2(d20, d21);
    }
  }
}

// ---------------- Layer-2 gather: 16 lanes/node, 2 lanes/edge (8B), pipelined ----
__global__ __launch_bounds__(TB) void
gat_gather2(const int* __restrict__ rowptr, const int* __restrict__ csr,
            const unsigned* __restrict__ hb2, const unsigned* __restrict__ ab2,
            const float* __restrict__ ald2,
            const void* __restrict__ bias,
            void* __restrict__ outp, int n, const int* __restrict__ flag) {
  const int isf = *flag;
  __shared__ float sb[8];
  if (threadIdx.x < 8) sb[threadIdx.x] = ldany(bias, threadIdx.x, isf);
  __syncthreads();

  const int t = blockIdx.x * TB + threadIdx.x;
  const int sub = t & 15, nid = t >> 4;
  const int slot = sub >> 1, hq = sub & 1;      // 8 edge slots x 2 head-lanes
  const bool act = nid < n;
  int beg = 0, end = 0;
  float aldv = 0.f;
  if (act) {
    beg = rowptr[nid];
    end = rowptr[nid + 1];
    aldv = ald2[(size_t)nid * 2 + hq];
  }

  float a0 = 0.f, a1 = 0.f, a2 = 0.f, a3 = 0.f, z = 0.f;

  int k  = beg + slot;
  int kn = k + 8;
  int s_cur = (k  < end) ? csr[k]  : 0;
  int s_nxt = (kn < end) ? csr[kn] : 0;
  uint2    u_cur = *(const uint2*)(hb2 + (size_t)s_cur * 4 + hq * 2);
  unsigned ab_cur = ab2[s_cur];
  while (k < end) {
    uint2    u_n = *(const uint2*)(hb2 + (size_t)s_nxt * 4 + hq * 2);
    unsigned ab_n = ab2[s_nxt];
    int kf = kn + 8;
    int s_f = (kf < end) ? csr[kf] : 0;
    float alsv = hq ? bf_hi(ab_cur) : bf_lo(ab_cur);
    float lg = alsv + aldv;
    lg = lg > 0.f ? lg : 0.2f * lg;
    float w = __expf(lg);
    z += w;
    a0 += w * bf_lo(u_cur.x); a1 += w * bf_hi(u_cur.x);
    a2 += w * bf_lo(u_cur.y); a3 += w * bf_hi(u_cur.y);
    k = kn; kn = kf; s_cur = s_nxt; s_nxt = s_f; u_cur = u_n; ab_cur = ab_n;
  }

  #pragma unroll
  for (int off = 2; off < 16; off <<= 1) {      // combine slots, keep head bit
    z  += __shfl_xor(z, off);
    a0 += __shfl_xor(a0, off); a1 += __shfl_xor(a1, off);
    a2 += __shfl_xor(a2, off); a3 += __shfl_xor(a3, off);
  }

  if (act && slot == 0) {                       // lanes sub=0(head0),1(head1)
    float inv = 1.f / (z + 1e-16f);
    float v0 = a0 * inv + sb[hq * 4 + 0];
    float v1 = a1 * inv + sb[hq * 4 + 1];
    float v2 = a2 * inv + sb[hq * 4 + 2];
    float v3 = a3 * inv + sb[hq * 4 + 3];
    if (isf) {
      ((float4*)outp)[(size_t)nid * 2 + hq] = make_float4(v0, v1, v2, v3);
    } else {
      ((uint2*)outp)[(size_t)nid * 2 + hq] = make_uint2(f2bf2(v0, v1), f2bf2(v2, v3));
    }
  }
}

extern "C" void kernel_launch(void* const* d_in, const int* in_sizes, int n_in,
                              void* d_out, int out_size, void* d_ws, size_t ws_size,
                              hipStream_t stream) {
  const void* x   = d_in[0];
  const int*  ei  = (const int*)d_in[1];
  const void* W1  = d_in[2];
  const void* as1 = d_in[3];
  const void* ad1 = d_in[4];
  const void* b1  = d_in[5];
  const void* W2  = d_in[6];
  const void* as2 = d_in[7];
  const void* ad2 = d_in[8];
  const void* b2  = d_in[9];

  const int n  = in_sizes[0] / 16;        // 100000
  const int E  = in_sizes[1] / 2;         // 3200000
  const int Et = E + n;                   // + self-loops
  const int NB = (n + BSZ - 1) >> BSH;    // 782 buckets
  const int EB = (Et + CHUNK - 1) / CHUNK;  // 806 edge-chunk blocks (<= EBP)

  // ---- workspace layout ----
  char* base = (char*)d_ws;
  int* flag   = (int*)base;               // 64 B
  int* gcnt   = (int*)(base + 64);        // NB+1
  int* gbase_ = gcnt + (NB + 1);          // NB+1
  int* rowptr = gbase_ + (NB + 1);        // n+1
  int* bcnt   = rowptr + (n + 1);         // NB * EBP (per-(bucket,block) counts)
  int* csr    = bcnt + (size_t)NB * EBP;  // Et (persists through both gathers)
  size_t off1 = 64 + sizeof(int) * ((size_t)(NB + 1) * 2 + (size_t)(n + 1)
                                    + (size_t)NB * EBP + (size_t)Et);
  off1 = (off1 + 255) & ~(size_t)255;
  // Union region: packed (Et ints, dead after localsort) / layer-1 bf16 tables
  // (44n bytes, written by gat_proj which runs after localsort).
  int*      packed = (int*)(base + off1);
  unsigned* hb1 = (unsigned*)(base + off1);        // 32n B: n x 16 bf16 (one 32B row)
  float*    ald1 = (float*)(base + off1 + (size_t)32 * n);   // 8n B: n x f32x2
  unsigned* ab1 = (unsigned*)(base + off1 + (size_t)40 * n); // 4n B: n x 2 bf16
  size_t usz = sizeof(int) * (size_t)Et;
  size_t fsz = (size_t)44 * n;
  size_t off2 = off1 + (usz > fsz ? usz : fsz);
  off2 = (off2 + 255) & ~(size_t)255;
  unsigned* hb2 = (unsigned*)(base + off2);        // 16n B: n x 8 bf16 (one 16B row)
  float*    ald2 = (float*)(base + off2 + (size_t)16 * n);   // 8n B
  unsigned* ab2 = (unsigned*)(base + off2 + (size_t)24 * n); // 4n B

  const int nblk   = (n + TB - 1) / TB;
  const int gblk16 = (16 * n + TB - 1) / TB;      // 16 threads per node

  detect_dtype<<<1, 64, 0, stream>>>((const unsigned short*)x, flag);

  // ---- bucket counting sort -> dst-sorted CSR (once; shared by both layers) ----
  k_bcount<<<EB, TBB, 0, stream>>>(ei, E, Et, NB, bcnt);
  k_blockpfx<<<NB, 1024, 0, stream>>>(bcnt, gcnt, EB, NB);
  k_bscan<<<1, 1024, 0, stream>>>(gcnt, gbase_, NB, Et);
  k_bscatter<<<EB, TBB, 0, stream>>>(ei, E, Et, NB, gbase_, bcnt, packed);
  k_localsort<<<NB, 512, 0, stream>>>(gbase_, packed, rowptr, csr, n, Et);

  // ---- Layer 1 proj (after localsort: hb1 overlaps packed) ----
  gat_proj<<<nblk, TB, 0, stream>>>(x, W1, as1, ad1, hb1, ab1, ald1, n, flag);

  // ---- Layer 1 gather + finalize + fused proj2 -> layer-2 tables ----
  gat_gather1<<<gblk16, TB, 0, stream>>>(rowptr, csr, hb1, ab1, ald1, b1,
                                         W2, as2, ad2, hb2, ab2, ald2, n, flag);

  // ---- Layer 2 gather + finalize -> d_out ----
  gat_gather2<<<gblk16, TB, 0, stream>>>(rowptr, csr, hb2, ab2, ald2, b2,
                                         d_out, n, flag);
}